// Round 7
// baseline (590.590 us; speedup 1.0000x reference)
//
#include <hip/hip_runtime.h>
#include <hip/hip_bf16.h>
#include <math.h>
#include <stdint.h>

#define B 2
#define S 4095
#define LSEQ 4096
#define F_IN 32
#define D 512
#define H 8
#define E 64
#define DFF 2048
#define NL 2
#define U 45
#define EPSL 1e-5f
#define LU (LSEQ * U)
#define HALF_LU (LU / 2)
#define NS 32
#define SLICE 128

typedef __attribute__((ext_vector_type(8))) short short8;
typedef __attribute__((ext_vector_type(4))) float f32x4;

#define GLD(gp, lp)                                                            \
    __builtin_amdgcn_global_load_lds(                                          \
        (const __attribute__((address_space(1))) void*)(gp),                   \
        (__attribute__((address_space(3))) void*)(lp), 16, 0, 0)

__device__ __forceinline__ unsigned short bf16_bits(float f) {
    __hip_bfloat16 h = __float2bfloat16(f);
    return *(unsigned short*)&h;
}
__device__ __forceinline__ float bits_to_f32(unsigned short s) {
    union { uint32_t u; float f; } c;
    c.u = ((uint32_t)s) << 16;
    return c.f;
}
// monotone sortable key: desc key order == (value desc, index asc) — JAX top_k ties
__device__ __forceinline__ unsigned long long mkey(float v, int index) {
    uint32_t u = __float_as_uint(v);
    uint32_t mono = (u & 0x80000000u) ? ~u : (u | 0x80000000u);
    return ((unsigned long long)mono << 32) | (uint32_t)(0xFFFFFFFFu - (uint32_t)index);
}

// ---------------- Threefry-2x32 (20 rounds), exactly JAX's algorithm ----------------
#define TF_BODY(k0, k1, c0, c1, o0, o1)                                        \
    do {                                                                       \
        uint32_t ks2 = (k0) ^ (k1) ^ 0x1BD11BDAu;                              \
        uint32_t x0 = (c0) + (k0), x1 = (c1) + (k1);                           \
        x0 += x1; x1 = ((x1 << 13) | (x1 >> 19)); x1 ^= x0;                    \
        x0 += x1; x1 = ((x1 << 15) | (x1 >> 17)); x1 ^= x0;                    \
        x0 += x1; x1 = ((x1 << 26) | (x1 >> 6));  x1 ^= x0;                    \
        x0 += x1; x1 = ((x1 << 6) | (x1 >> 26));  x1 ^= x0;                    \
        x0 += (k1); x1 += ks2 + 1u;                                            \
        x0 += x1; x1 = ((x1 << 17) | (x1 >> 15)); x1 ^= x0;                    \
        x0 += x1; x1 = ((x1 << 29) | (x1 >> 3));  x1 ^= x0;                    \
        x0 += x1; x1 = ((x1 << 16) | (x1 >> 16)); x1 ^= x0;                    \
        x0 += x1; x1 = ((x1 << 24) | (x1 >> 8));  x1 ^= x0;                    \
        x0 += ks2; x1 += (k0) + 2u;                                            \
        x0 += x1; x1 = ((x1 << 13) | (x1 >> 19)); x1 ^= x0;                    \
        x0 += x1; x1 = ((x1 << 15) | (x1 >> 17)); x1 ^= x0;                    \
        x0 += x1; x1 = ((x1 << 26) | (x1 >> 6));  x1 ^= x0;                    \
        x0 += x1; x1 = ((x1 << 6) | (x1 >> 26));  x1 ^= x0;                    \
        x0 += (k0); x1 += (k1) + 3u;                                           \
        x0 += x1; x1 = ((x1 << 17) | (x1 >> 15)); x1 ^= x0;                    \
        x0 += x1; x1 = ((x1 << 29) | (x1 >> 3));  x1 ^= x0;                    \
        x0 += x1; x1 = ((x1 << 16) | (x1 >> 16)); x1 ^= x0;                    \
        x0 += x1; x1 = ((x1 << 24) | (x1 >> 8));  x1 ^= x0;                    \
        x0 += (k1); x1 += ks2 + 4u;                                            \
        x0 += x1; x1 = ((x1 << 13) | (x1 >> 19)); x1 ^= x0;                    \
        x0 += x1; x1 = ((x1 << 15) | (x1 >> 17)); x1 ^= x0;                    \
        x0 += x1; x1 = ((x1 << 26) | (x1 >> 6));  x1 ^= x0;                    \
        x0 += x1; x1 = ((x1 << 6) | (x1 >> 26));  x1 ^= x0;                    \
        x0 += ks2; x1 += (k0) + 5u;                                            \
        (o0) = x0; (o1) = x1;                                                  \
    } while (0)

__device__ __forceinline__ void threefry_dev(uint32_t k0, uint32_t k1, uint32_t c0,
                                             uint32_t c1, uint32_t& o0, uint32_t& o1) {
    TF_BODY(k0, k1, c0, c1, o0, o1);
}
static void threefry_host(uint32_t k0, uint32_t k1, uint32_t c0, uint32_t c1,
                          uint32_t& o0, uint32_t& o1) {
    TF_BODY(k0, k1, c0, c1, o0, o1);
}

// ------- FUSED embed: h_bf = bf16((l==0 ? cls : bf16(x_row)·bf16(We)^T + be) + PE) -
// Replaces prep_embed + gemm32(K=32, latency-bound ~13us) + posenc (~5us) and the
// 32MB f32 emb round-trip with ONE elementwise-style kernel: block = one row,
// x-row staged in LDS (bf16-rounded — same bits as the old xbf), 32 scalar FMAs
// per output on bf16-rounded We (same bits as old webf), f32 accum, + posenc.
__global__ __launch_bounds__(256) void embed_posenc_kernel(
        const float* __restrict__ x, const float* __restrict__ We,
        const float* __restrict__ be, const float* __restrict__ cls,
        __hip_bfloat16* __restrict__ hbf) {
    int row = blockIdx.x;
    int b = row >> 12;
    int l = row & (LSEQ - 1);
    int tid = threadIdx.x;
    __shared__ float xs[F_IN];
    if (l > 0 && tid < F_IN)
        xs[tid] = bits_to_f32(bf16_bits(x[((size_t)b * S + (l - 1)) * F_IN + tid]));
    __syncthreads();
#pragma unroll
    for (int hh = 0; hh < 2; ++hh) {
        int n = tid + hh * 256;
        float v;
        if (l == 0) {
            v = cls[n];
        } else {
            const float* wr = We + (size_t)n * F_IN;
            float acc = 0.f;
#pragma unroll
            for (int k = 0; k < F_IN; ++k)
                acc += xs[k] * bits_to_f32(bf16_bits(wr[k]));
            v = acc + be[n];
        }
        int i2 = n >> 1;
        float divv = expf((float)(2 * i2) * (float)(-9.210340371976184 / 512.0));
        float ang = (float)l * divv;
        v += (n & 1) ? cosf(ang) : sinf(ang);
        hbf[(size_t)row * D + n] = __float2bfloat16(v);
    }
}

// ------- dual-layer weight cast + packed qkv bias (pre-loop, blockIdx.y = layer) ---
__global__ void cast_weights_kernel(const float* __restrict__ Wq,
                                    const float* __restrict__ Wk,
                                    const float* __restrict__ Wv,
                                    const float* __restrict__ Wo,
                                    const float* __restrict__ W1,
                                    const float* __restrict__ W2,
                                    const float* __restrict__ bq,
                                    const float* __restrict__ bk,
                                    const float* __restrict__ bv,
                                    __hip_bfloat16* __restrict__ wpool,
                                    float* __restrict__ qkvbias) {
    const int SDD = D * D / 4;       // 65536
    const int SFD = DFF * D / 4;     // 262144
    const int CAST_N = 4 * SDD + 2 * SFD;
    const size_t WPL = (size_t)4 * D * D + 2 * (size_t)DFF * D;  // bf16 elems/layer
    int l = blockIdx.y;
    int u = blockIdx.x * blockDim.x + threadIdx.x;
    __hip_bfloat16* base = wpool + (size_t)l * WPL;
    if (u >= CAST_N) {
        int j = u - CAST_N;
        if (j < 384) {               // packed qkv bias, 4-float units over 1536
            int seg = (j * 4) >> 9;  // 0:q 1:k 2:v
            int off = (j * 4) & 511;
            const float* src = (seg == 0) ? bq + l * D
                             : (seg == 1) ? bk + l * D : bv + l * D;
            *(float4*)(qkvbias + l * 1536 + j * 4) = *(const float4*)(src + off);
        }
        return;
    }
    const float* src;
    __hip_bfloat16* dst;
    int off;
    if (u < SDD)            { src = Wq + (size_t)l * D * D;   dst = base;                       off = u; }
    else if (u < 2 * SDD)   { src = Wk + (size_t)l * D * D;   dst = base + (size_t)D * D;       off = u - SDD; }
    else if (u < 3 * SDD)   { src = Wv + (size_t)l * D * D;   dst = base + (size_t)2 * D * D;   off = u - 2 * SDD; }
    else if (u < 4 * SDD)   { src = Wo + (size_t)l * D * D;   dst = base + (size_t)3 * D * D;   off = u - 3 * SDD; }
    else if (u < 4 * SDD + SFD) { src = W1 + (size_t)l * DFF * D; dst = base + (size_t)4 * D * D; off = u - 4 * SDD; }
    else { src = W2 + (size_t)l * D * DFF; dst = base + (size_t)4 * D * D + (size_t)DFF * D; off = u - 4 * SDD - SFD; }
    float4 v = ((const float4*)src)[off];
    union { unsigned short s[4]; uint2 w; } o;
    o.s[0] = bf16_bits(v.x); o.s[1] = bf16_bits(v.y);
    o.s[2] = bf16_bits(v.z); o.s[3] = bf16_bits(v.w);
    ((uint2*)dst)[off] = o.w;
}

// ------- PIPELINED bf16 MFMA GEMM, 128x128 tile, BK=32, dbuf, XCD-swizzled ---------
// MODE 1: bf16 out; 2: relu->bf16; 3: QKV (all three outputs bf16, segments of 512)
template <int MODE>
__global__ __launch_bounds__(256) void gemm_pipe(const unsigned short* __restrict__ A,
                                                 const unsigned short* __restrict__ W,
                                                 const float* __restrict__ bias,
                                                 void* __restrict__ C0,
                                                 void* __restrict__ C1,
                                                 void* __restrict__ C2,
                                                 int M, int N, int K, int NBN) {
    __shared__ unsigned short As[2][128 * 32];
    __shared__ unsigned short Bs[2][128 * 32];
    const int tid = threadIdx.x;
    const int NBM = M >> 7;
    const int bid = blockIdx.x;
    const int xcd = bid & 7, local = bid >> 3;
    const int m_t = xcd * (NBM >> 3) + local / NBN;
    const int n_t = local % NBN;
    const int m0 = m_t * 128, n0 = n_t * 128;
    const int wave = tid >> 6, lane = tid & 63;
    const int wm = (wave >> 1) * 64, wn = (wave & 1) * 64;
    const int quad = lane >> 4, m15 = lane & 15;
    const int srow = tid >> 2, scol = (tid & 3) * 8;
    f32x4 acc[4][4] = {};
    const unsigned short* Ag0 = A + (size_t)(m0 + srow) * K + scol;
    const unsigned short* Ag1 = A + (size_t)(m0 + srow + 64) * K + scol;
    const unsigned short* Wg0 = W + (size_t)(n0 + srow) * K + scol;
    const unsigned short* Wg1 = W + (size_t)(n0 + srow + 64) * K + scol;
    GLD(Ag0, As[0] + tid * 8);
    GLD(Ag1, As[0] + 2048 + tid * 8);
    GLD(Wg0, Bs[0] + tid * 8);
    GLD(Wg1, Bs[0] + 2048 + tid * 8);
    int cur = 0;
    for (int k0 = 0; k0 < K; k0 += 32) {
        __syncthreads();
        int kn = k0 + 32;
        if (kn < K) {
            GLD(Ag0 + kn, As[cur ^ 1] + tid * 8);
            GLD(Ag1 + kn, As[cur ^ 1] + 2048 + tid * 8);
            GLD(Wg0 + kn, Bs[cur ^ 1] + tid * 8);
            GLD(Wg1 + kn, Bs[cur ^ 1] + 2048 + tid * 8);
        }
        short8 af[4], bfr[4];
#pragma unroll
        for (int mi = 0; mi < 4; ++mi)
            af[mi] = *(const short8*)(As[cur] + (wm + mi * 16 + m15) * 32 + quad * 8);
#pragma unroll
        for (int ni = 0; ni < 4; ++ni)
            bfr[ni] = *(const short8*)(Bs[cur] + (wn + ni * 16 + m15) * 32 + quad * 8);
#pragma unroll
        for (int mi = 0; mi < 4; ++mi)
#pragma unroll
            for (int ni = 0; ni < 4; ++ni)
                acc[mi][ni] = __builtin_amdgcn_mfma_f32_16x16x32_bf16(
                    af[mi], bfr[ni], acc[mi][ni], 0, 0, 0);
        cur ^= 1;
    }
#pragma unroll
    for (int mi = 0; mi < 4; ++mi) {
        int mg = m0 + wm + mi * 16 + quad * 4;
#pragma unroll
        for (int ni = 0; ni < 4; ++ni) {
            int ng = n0 + wn + ni * 16 + m15;
            float bv = bias[ng];
#pragma unroll
            for (int r = 0; r < 4; ++r) {
                float v = acc[mi][ni][r] + bv;
                if (MODE == 1) {
                    ((__hip_bfloat16*)C0)[(size_t)(mg + r) * N + ng] = __float2bfloat16(v);
                } else if (MODE == 2) {
                    ((__hip_bfloat16*)C0)[(size_t)(mg + r) * N + ng] =
                        __float2bfloat16(fmaxf(v, 0.f));
                } else {  // QKV: N=1536, segments of 512, all bf16
                    int seg = ng >> 9;
                    int col = ng & 511;
                    __hip_bfloat16* dst = (seg == 0) ? (__hip_bfloat16*)C0
                                        : (seg == 1) ? (__hip_bfloat16*)C1
                                                     : (__hip_bfloat16*)C2;
                    dst[(size_t)(mg + r) * D + col] = __float2bfloat16(v);
                }
            }
        }
    }
}

// ------- W2 GEMM: m97-shape 128x128 BK=32 pipelined + split-K=2, f32 out -----------
__global__ __launch_bounds__(256) void gemm_w2b(const unsigned short* __restrict__ A,
                                                const unsigned short* __restrict__ W,
                                                const float* __restrict__ bias,
                                                float* __restrict__ C0,
                                                float* __restrict__ C1) {
    const int K = 2048, N = 512, KH = 1024;
    __shared__ unsigned short As[2][128 * 32];
    __shared__ unsigned short Bs[2][128 * 32];
    const int tid = threadIdx.x;
    const int bid = blockIdx.x;
    const int xcd = bid & 7, local = bid >> 3;
    const int m_t = xcd * 8 + (local >> 3);
    const int n_t = (local >> 1) & 3;
    const int ks = local & 1;
    const int m0 = m_t * 128, n0 = n_t * 128, kb = ks * KH;
    const int wave = tid >> 6, lane = tid & 63;
    const int wm = (wave >> 1) * 64, wn = (wave & 1) * 64;
    const int quad = lane >> 4, m15 = lane & 15;
    const int srow = tid >> 2, scol = (tid & 3) * 8;
    f32x4 acc[4][4] = {};
    const unsigned short* Ag0 = A + (size_t)(m0 + srow) * K + kb + scol;
    const unsigned short* Ag1 = A + (size_t)(m0 + srow + 64) * K + kb + scol;
    const unsigned short* Wg0 = W + (size_t)(n0 + srow) * K + kb + scol;
    const unsigned short* Wg1 = W + (size_t)(n0 + srow + 64) * K + kb + scol;
    GLD(Ag0, As[0] + tid * 8);
    GLD(Ag1, As[0] + 2048 + tid * 8);
    GLD(Wg0, Bs[0] + tid * 8);
    GLD(Wg1, Bs[0] + 2048 + tid * 8);
    int cur = 0;
    for (int k0 = 0; k0 < KH; k0 += 32) {
        __syncthreads();
        int kn = k0 + 32;
        if (kn < KH) {
            GLD(Ag0 + kn, As[cur ^ 1] + tid * 8);
            GLD(Ag1 + kn, As[cur ^ 1] + 2048 + tid * 8);
            GLD(Wg0 + kn, Bs[cur ^ 1] + tid * 8);
            GLD(Wg1 + kn, Bs[cur ^ 1] + 2048 + tid * 8);
        }
        short8 af[4], bfr[4];
#pragma unroll
        for (int mi = 0; mi < 4; ++mi)
            af[mi] = *(const short8*)(As[cur] + (wm + mi * 16 + m15) * 32 + quad * 8);
#pragma unroll
        for (int ni = 0; ni < 4; ++ni)
            bfr[ni] = *(const short8*)(Bs[cur] + (wn + ni * 16 + m15) * 32 + quad * 8);
#pragma unroll
        for (int mi = 0; mi < 4; ++mi)
#pragma unroll
            for (int ni = 0; ni < 4; ++ni)
                acc[mi][ni] = __builtin_amdgcn_mfma_f32_16x16x32_bf16(
                    af[mi], bfr[ni], acc[mi][ni], 0, 0, 0);
        cur ^= 1;
    }
    float* Cf = ks ? C1 : C0;
#pragma unroll
    for (int mi = 0; mi < 4; ++mi) {
        int mg = m0 + wm + mi * 16 + quad * 4;
#pragma unroll
        for (int ni = 0; ni < 4; ++ni) {
            int ng = n0 + wn + ni * 16 + m15;
            float bv = ks ? 0.f : bias[ng];
#pragma unroll
            for (int r = 0; r < 4; ++r)
                Cf[(size_t)(mg + r) * N + ng] = acc[mi][ni][r] + bv;
        }
    }
}

// -------- M-score: block per (b,l); 3-deep unrolled K-row gather -------------------
__global__ __launch_bounds__(256) void mscore_kernel(const __hip_bfloat16* __restrict__ qbf,
                                                     const __hip_bfloat16* __restrict__ kbf,
                                                     uint32_t k2a, uint32_t k2b,
                                                     float* __restrict__ Mv) {
    __shared__ float Sbuf[U][8];
    __shared__ int sidx[U];
    int bid = blockIdx.x;
    int b = bid & 1;
    int l = bid >> 1;
    int tid = threadIdx.x;
    int wave = tid >> 6, lane = tid & 63;
    if (tid < U) {
        int i = l * U + tid;
        uint32_t c0 = (i < HALF_LU) ? (uint32_t)i : (uint32_t)(i - HALF_LU);
        uint32_t o0, o1;
        threefry_dev(k2a, k2b, c0, c0 + HALF_LU, o0, o1);
        sidx[tid] = (int)(((i < HALF_LU) ? o0 : o1) & 4095u);
    }
    const unsigned short* qr =
        (const unsigned short*)qbf + ((size_t)(b * LSEQ) + l) * D + lane * 8;
    union { uint4 u; unsigned short s[8]; } qv;
    qv.u = *(const uint4*)qr;
    float qa[8];
#pragma unroll
    for (int j = 0; j < 8; ++j) qa[j] = bits_to_f32(qv.s[j]);
    __syncthreads();
    const unsigned short* kbase = (const unsigned short*)(kbf + (size_t)(b * LSEQ) * D);
    for (int t = wave; t < U; t += 12) {
        int tb = t + 4, tc = t + 8;
        bool hb = tb < U, hc = tc < U;
        union { uint4 u; unsigned short s[8]; } kva, kvb, kvc;
        kva.u = *(const uint4*)(kbase + (size_t)sidx[t] * D + lane * 8);
        if (hb) kvb.u = *(const uint4*)(kbase + (size_t)sidx[tb] * D + lane * 8);
        if (hc) kvc.u = *(const uint4*)(kbase + (size_t)sidx[tc] * D + lane * 8);
        {
            float p = 0.f;
#pragma unroll
            for (int j = 0; j < 8; ++j) p += qa[j] * bits_to_f32(kva.s[j]);
            p += __shfl_xor(p, 1);
            p += __shfl_xor(p, 2);
            p += __shfl_xor(p, 4);
            if ((lane & 7) == 0) Sbuf[t][lane >> 3] = p;
        }
        if (hb) {
            float p = 0.f;
#pragma unroll
            for (int j = 0; j < 8; ++j) p += qa[j] * bits_to_f32(kvb.s[j]);
            p += __shfl_xor(p, 1);
            p += __shfl_xor(p, 2);
            p += __shfl_xor(p, 4);
            if ((lane & 7) == 0) Sbuf[tb][lane >> 3] = p;
        }
        if (hc) {
            float p = 0.f;
#pragma unroll
            for (int j = 0; j < 8; ++j) p += qa[j] * bits_to_f32(kvc.s[j]);
            p += __shfl_xor(p, 1);
            p += __shfl_xor(p, 2);
            p += __shfl_xor(p, 4);
            if ((lane & 7) == 0) Sbuf[tc][lane >> 3] = p;
        }
    }
    __syncthreads();
    if (tid < 8) {
        float mx = -INFINITY, sm = 0.f;
        for (int t = 0; t < U; ++t) {
            float v = Sbuf[t][tid];
            mx = fmaxf(mx, v);
            sm += v;
        }
        Mv[((size_t)b * H + tid) * LSEQ + l] = mx - sm / (float)LSEQ;
    }
}

// ------- top-k phase A: bitonic sort each 256-chunk desc, emit top-45 keys ---------
__global__ __launch_bounds__(256) void topk_chunk_kernel(const float* __restrict__ Mv,
                                                         unsigned long long* __restrict__ cand) {
    __shared__ unsigned long long sk[256];
    int blk = blockIdx.x;  // B*H*16
    int chunk = blk & 15, bh = blk >> 4;
    int tid = threadIdx.x;
    int gi = chunk * 256 + tid;
    sk[tid] = mkey(Mv[(size_t)bh * LSEQ + gi], gi);
    __syncthreads();
    for (int k = 2; k <= 256; k <<= 1) {
        for (int j = k >> 1; j > 0; j >>= 1) {
            int ixj = tid ^ j;
            if (ixj > tid) {
                unsigned long long a = sk[tid], b = sk[ixj];
                bool desc = ((tid & k) == 0);
                if (desc ? (a < b) : (a > b)) { sk[tid] = b; sk[ixj] = a; }
            }
            __syncthreads();
        }
    }
    if (tid < U) cand[((size_t)bh * 16 + chunk) * U + tid] = sk[tid];
}

// ------- FUSED: top-k merge [0,16) ∥ vmean partial [16,144) ∥ flag clear [144,152) -
__global__ __launch_bounds__(256) void topkmerge_vmean_kernel(
        const unsigned long long* __restrict__ cand, int* __restrict__ top,
        const __hip_bfloat16* __restrict__ v, float* __restrict__ part,
        unsigned char* __restrict__ flags) {
    __shared__ unsigned long long sk[1024];
    __shared__ float red[4][64];
    int blk = blockIdx.x;
    int tid = threadIdx.x;
    if (blk < B * H) {  // ---- topk_merge role ----
        int bh = blk;
        for (int e = tid; e < 1024; e += 256)
            sk[e] = (e < 16 * U) ? cand[(size_t)bh * 16 * U + e] : 0ull;
        __syncthreads();
        for (int k = 2; k <= 1024; k <<= 1) {
            for (int j = k >> 1; j > 0; j >>= 1) {
                for (int e = tid; e < 1024; e += 256) {
                    int ixj = e ^ j;
                    if (ixj > e) {
                        unsigned long long a = sk[e], b = sk[ixj];
                        bool desc = ((e & k) == 0);
                        if (desc ? (a < b) : (a > b)) { sk[e] = b; sk[ixj] = a; }
                    }
                }
                __syncthreads();
            }
        }
        if (tid < U)
            top[bh * U + tid] = (int)(0xFFFFFFFFu - (uint32_t)(sk[tid] & 0xFFFFFFFFu));
    } else if (blk < B * H + B * H * 8) {  // ---- vmean_part role ----
        int vb = blk - B * H;  // 0..127
        int seg = vb & 7, hh = (vb >> 3) & 7, b = vb >> 6;
        int e = tid & 63, rg = tid >> 6;
        const __hip_bfloat16* vp =
            v + ((size_t)(b * LSEQ) + seg * 512) * D + hh * 64 + e;
        float acc = 0.f;
        for (int r = rg; r < 512; r += 4) acc += __bfloat162float(vp[(size_t)r * D]);
        red[rg][e] = acc;
        __syncthreads();
        if (tid < 64)
            part[(size_t)vb * 64 + tid] =
                red[0][tid] + red[1][tid] + red[2][tid] + red[3][tid];
    } else {  // ---- flag clear role: 8 blocks x 256 x 4B = 8192 B ----
        int fb = blk - (B * H + B * H * 8);
        ((int*)flags)[fb * 256 + tid] = 0;
    }
}

// ------- FUSED: zero selected aout rows (blocks [0,720)) ∥ wo_base (blocks [720,976))
__global__ __launch_bounds__(256) void zero_wobase_kernel(
        const int* __restrict__ top, float* __restrict__ aout,
        unsigned char* __restrict__ flags, const float* __restrict__ vpart,
        const unsigned short* __restrict__ wob, const float* __restrict__ bo,
        float* __restrict__ base) {
    int bid = blockIdx.x;
    int tid = threadIdx.x;
    if (bid < B * H * U) {  // ---- zero_corr role ----
        int t = bid % U;
        int bh = bid / U;
        int b = bh >> 3;
        int r = top[bh * U + t];
        if (tid < 128) {
            float4 z = {0.f, 0.f, 0.f, 0.f};
            ((float4*)(aout + (size_t)(b * LSEQ + r) * D))[tid] = z;
        }
        if (tid == 0) flags[b * LSEQ + r] = 1;
    } else {  // ---- wo_base role ----
        int wb = bid - B * H * U;           // 0..255
        int b = wb >> 7;
        int n = (wb & 127) * 4 + (tid >> 6);
        int lane = tid & 63;
        float vmv[8];
#pragma unroll
        for (int j = 0; j < 8; ++j) {
            int idx = lane * 8 + j;
            int hh = idx >> 6, e = idx & 63;
            float acc = 0.f;
#pragma unroll
            for (int s = 0; s < 8; ++s)
                acc += vpart[((size_t)(b * 8 + hh) * 8 + s) * 64 + e];
            vmv[j] = acc / (float)LSEQ;
        }
        union { uint4 u; unsigned short s[8]; } w;
        w.u = *(const uint4*)(wob + (size_t)n * D + lane * 8);
        float p = vmv[0] * bits_to_f32(w.s[0]) + vmv[1] * bits_to_f32(w.s[1]) +
                  vmv[2] * bits_to_f32(w.s[2]) + vmv[3] * bits_to_f32(w.s[3]) +
                  vmv[4] * bits_to_f32(w.s[4]) + vmv[5] * bits_to_f32(w.s[5]) +
                  vmv[6] * bits_to_f32(w.s[6]) + vmv[7] * bits_to_f32(w.s[7]);
        for (int off = 32; off; off >>= 1) p += __shfl_xor(p, off);
        if (lane == 0) base[(size_t)b * D + n] = p + bo[n];
    }
}

// ------- merged: combine slice partials -> dlt; scatter Wo correction --------------
__global__ __launch_bounds__(256) void attnred_corr_kernel(const float* __restrict__ Opart,
                                                           const float* __restrict__ msum,
                                                           const float* __restrict__ vpart,
                                                           const unsigned short* __restrict__ wob,
                                                           const int* __restrict__ top,
                                                           float* __restrict__ aout) {
    __shared__ float dlt[E];
    int bid = blockIdx.x;  // B*H*U
    int t = bid % U;
    int bh = bid / U;
    int b = bh >> 3, hh = bh & 7;
    int tid = threadIdx.x;
    if (tid < 64) {
        int lane = tid;
        float m_s = -INFINITY, ss = 0.f;
        if (lane < NS) {
            size_t base = (((size_t)bh * NS + lane) * U + t) * 2;
            m_s = msum[base];
            ss = msum[base + 1];
        }
        float M = m_s;
        for (int off = 32; off; off >>= 1) M = fmaxf(M, __shfl_xor(M, off));
        float e_s = (lane < NS) ? __expf(m_s - M) : 0.f;
        float d = ss * e_s;
        for (int off = 32; off; off >>= 1) d += __shfl_xor(d, off);
        float acc = 0.f;
        for (int s = 0; s < NS; ++s) {
            float w = __shfl(e_s, s);
            acc += w * Opart[(((size_t)bh * NS + s) * U + t) * 64 + lane];
        }
        float vmv = 0.f;
#pragma unroll
        for (int s = 0; s < 8; ++s) vmv += vpart[((size_t)bh * 8 + s) * 64 + lane];
        dlt[lane] = acc / d - vmv / (float)LSEQ;
    }
    __syncthreads();
    int r = top[bh * U + t];
    float* arow = aout + (size_t)(b * LSEQ + r) * D;
    for (int n = tid; n < D; n += 256) {
        const unsigned short* wr = wob + (size_t)n * D + hh * E;
        float acc = 0.f;
#pragma unroll
        for (int v4 = 0; v4 < 8; ++v4) {
            union { uint4 u; unsigned short s[8]; } w;
            w.u = *(const uint4*)(wr + v4 * 8);
#pragma unroll
            for (int j = 0; j < 8; ++j)
                acc += dlt[v4 * 8 + j] * bits_to_f32(w.s[j]);
        }
        atomicAdd(arow + n, acc);
    }
}

// -------- flash-style MFMA attention partial: block = (slice, h, b) ----------------
__global__ __launch_bounds__(256) void attn_part(const __hip_bfloat16* __restrict__ qbf,
                                                 const __hip_bfloat16* __restrict__ kbf,
                                                 const __hip_bfloat16* __restrict__ vbf,
                                                 const int* __restrict__ top,
                                                 float* __restrict__ Opart,
                                                 float* __restrict__ msum) {
    __shared__ unsigned short Qs[48 * 72];
    __shared__ unsigned short Ks[SLICE * 72];
    __shared__ unsigned short Vs[SLICE * 68];
    __shared__ unsigned short Ps[48 * 136];
    __shared__ float mred[48][4];
    __shared__ float sred[48][4];
    const int slice = blockIdx.x, hh = blockIdx.y, b = blockIdx.z;
    const int bh = b * H + hh;
    const int tid = threadIdx.x;
    const int s0 = slice * SLICE;
    for (int i = tid; i < 48 * 64; i += 256) {
        int t = i >> 6, e = i & 63;
        unsigned short v = 0;
        if (t < U) {
            int r = top[bh * U + t];
            v = ((const unsigned short*)qbf)[((size_t)(b * LSEQ) + r) * D + hh * E + e];
        }
        Qs[t * 72 + e] = v;
    }
    {
        const uint4* src = (const uint4*)(kbf + ((size_t)(b * LSEQ) + s0) * D + hh * E);
        for (int i = tid; i < SLICE * 8; i += 256) {
            int r = i >> 3, c = i & 7;
            uint4 d = src[(size_t)r * 64 + c];
            *(uint4*)(Ks + r * 72 + c * 8) = d;
        }
    }
    {
        const uint2* src = (const uint2*)(vbf + ((size_t)(b * LSEQ) + s0) * D + hh * E);
        for (int i = tid; i < SLICE * 16; i += 256) {
            int r = i >> 4, c = i & 15;
            uint2 d = src[(size_t)r * 128 + c];
            *(uint2*)(Vs + r * 68 + c * 4) = d;
        }
    }
    __syncthreads();
    const int wave = tid >> 6, lane = tid & 63;
    const int quad = lane >> 4, m15 = lane & 15;
    const int wc = wave * 32;
    f32x4 acc[3][2] = {};
#pragma unroll
    for (int ks = 0; ks < 2; ++ks) {
        short8 af[3], bfr[2];
#pragma unroll
        for (int mt = 0; mt < 3; ++mt)
            af[mt] = *(const short8*)(Qs + (mt * 16 + m15) * 72 + ks * 32 + quad * 8);
#pragma unroll
        for (int nt = 0; nt < 2; ++nt)
            bfr[nt] = *(const short8*)(Ks + (wc + nt * 16 + m15) * 72 + ks * 32 + quad * 8);
#pragma unroll
        for (int mt = 0; mt < 3; ++mt)
#pragma unroll
            for (int nt = 0; nt < 2; ++nt)
                acc[mt][nt] = __builtin_amdgcn_mfma_f32_16x16x32_bf16(
                    af[mt], bfr[nt], acc[mt][nt], 0, 0, 0);
    }
    float sc[3][2][4];
#pragma unroll
    for (int mt = 0; mt < 3; ++mt)
#pragma unroll
        for (int nt = 0; nt < 2; ++nt)
#pragma unroll
            for (int r = 0; r < 4; ++r) sc[mt][nt][r] = acc[mt][nt][r] * 0.125f;
#pragma unroll
    for (int mt = 0; mt < 3; ++mt)
#pragma unroll
        for (int r = 0; r < 4; ++r) {
            float mv = fmaxf(sc[mt][0][r], sc[mt][1][r]);
            mv = fmaxf(mv, __shfl_xor(mv, 1));
            mv = fmaxf(mv, __shfl_xor(mv, 2));
            mv = fmaxf(mv, __shfl_xor(mv, 4));
            mv = fmaxf(mv, __shfl_xor(mv, 8));
            if (m15 == 0) mred[mt * 16 + quad * 4 + r][wave] = mv;
        }
    __syncthreads();
#pragma unroll
    for (int mt = 0; mt < 3; ++mt)
#pragma unroll
        for (int r = 0; r < 4; ++r) {
            int row = mt * 16 + quad * 4 + r;
            float ms = fmaxf(fmaxf(mred[row][0], mred[row][1]),
                             fmaxf(mred[row][2], mred[row][3]));
            float p0 = __expf(sc[mt][0][r] - ms);
            float p1 = __expf(sc[mt][1][r] - ms);
            float sv = p0 + p1;
            sv += __shfl_xor(sv, 1);
            sv += __shfl_xor(sv, 2);
            sv += __shfl_xor(sv, 4);
            sv += __shfl_xor(sv, 8);
            if (m15 == 0) sred[row][wave] = sv;
            Ps[row * 136 + wc + m15] = bf16_bits(p0);
            Ps[row * 136 + wc + 16 + m15] = bf16_bits(p1);
        }
    __syncthreads();
    if (tid < U) {
        float mm = fmaxf(fmaxf(mred[tid][0], mred[tid][1]),
                         fmaxf(mred[tid][2], mred[tid][3]));
        float ss = sred[tid][0] + sred[tid][1] + sred[tid][2] + sred[tid][3];
        size_t base = (((size_t)bh * NS + slice) * U + tid) * 2;
        msum[base] = mm;
        msum[base + 1] = ss;
    }
    f32x4 apv[3] = {};
#pragma unroll
    for (int ks = 0; ks < 4; ++ks) {
        short8 bv;
#pragma unroll
        for (int j = 0; j < 8; ++j)
            bv[j] = (short)Vs[(ks * 32 + quad * 8 + j) * 68 + wave * 16 + m15];
        short8 af2[3];
#pragma unroll
        for (int mt = 0; mt < 3; ++mt)
            af2[mt] = *(const short8*)(Ps + (mt * 16 + m15) * 136 + ks * 32 + quad * 8);
#pragma unroll
        for (int mt = 0; mt < 3; ++mt)
            apv[mt] = __builtin_amdgcn_mfma_f32_16x16x32_bf16(af2[mt], bv, apv[mt], 0, 0, 0);
    }
    size_t obase = ((size_t)bh * NS + slice) * U;
#pragma unroll
    for (int mt = 0; mt < 3; ++mt)
#pragma unroll
        for (int r = 0; r < 4; ++r) {
            int row = mt * 16 + quad * 4 + r;
            if (row < U)
                Opart[(obase + row) * 64 + wave * 16 + m15] = apv[mt][r];
        }
}

// -------- LN1: hbf = LayerNorm(hbf + base[b] + sparse corr) * g + b (bf16 stream) --
__global__ __launch_bounds__(64) void add_ln_base_kernel(__hip_bfloat16* __restrict__ hbf,
                                                         const float* __restrict__ base,
                                                         const float* __restrict__ aout,
                                                         const unsigned char* __restrict__ flags,
                                                         const float* __restrict__ g,
                                                         const float* __restrict__ bb) {
    int row = blockIdx.x;
    int b = row >> 12;
    int lane = threadIdx.x;
    unsigned short* hp = (unsigned short*)hbf + (size_t)row * D;
    const float* bp = base + (size_t)b * D;
    const float* ap = aout + (size_t)row * D;
    bool has = flags[row] != 0;
    float x[8];
    float sum = 0.f;
#pragma unroll
    for (int j = 0; j < 8; ++j) {
        float a = bp[lane + 64 * j];
        if (has) a += ap[lane + 64 * j];
        x[j] = bits_to_f32(hp[lane + 64 * j]) + a;
        sum += x[j];
    }
    for (int off = 32; off; off >>= 1) sum += __shfl_xor(sum, off);
    float mu = sum / (float)D;
    float vs = 0.f;
#pragma unroll
    for (int j = 0; j < 8; ++j) {
        float dd = x[j] - mu;
        vs += dd * dd;
    }
    for (int off = 32; off; off >>= 1) vs += __shfl_xor(vs, off);
    float inv = 1.f / sqrtf(vs / (float)D + EPSL);
#pragma unroll
    for (int j = 0; j < 8; ++j) {
        float o = (x[j] - mu) * inv * g[lane + 64 * j] + bb[lane + 64 * j];
        hp[lane + 64 * j] = bf16_bits(o);
    }
}

// -------- LN2: hbf = LayerNorm(hbf + a + a2) * g + b; last layer fuses final head --
// (final_kernel eliminated: for row l==0 the block holds the full post-LN row in
//  registers with the same lane->j mapping and shuffle tree as final_kernel used,
//  so out[b] is computed here bit-identically on the last layer.)
__global__ __launch_bounds__(64) void add_ln_kernel(__hip_bfloat16* __restrict__ hbf,
                                                    const float* __restrict__ a,
                                                    const float* __restrict__ a2,
                                                    const float* __restrict__ g,
                                                    const float* __restrict__ bb,
                                                    const float* __restrict__ Wf,
                                                    const float* __restrict__ bf,
                                                    float* __restrict__ out,
                                                    int fuseFinal) {
    int row = blockIdx.x;
    int lane = threadIdx.x;
    unsigned short* hp = (unsigned short*)hbf + (size_t)row * D;
    const float* ap = a + (size_t)row * D;
    const float* ap2 = a2 + (size_t)row * D;
    float x[8];
    float sum = 0.f;
#pragma unroll
    for (int j = 0; j < 8; ++j) {
        x[j] = bits_to_f32(hp[lane + 64 * j]) + ap[lane + 64 * j] + ap2[lane + 64 * j];
        sum += x[j];
    }
    for (int off = 32; off; off >>= 1) sum += __shfl_xor(sum, off);
    float mu = sum / (float)D;
    float vs = 0.f;
#pragma unroll
    for (int j = 0; j < 8; ++j) {
        float dd = x[j] - mu;
        vs += dd * dd;
    }
    for (int off = 32; off; off >>= 1) vs += __shfl_xor(vs, off);
    float inv = 1.f / sqrtf(vs / (float)D + EPSL);
    bool doFinal = fuseFinal && ((row & (LSEQ - 1)) == 0);
    float facc = 0.f;
#pragma unroll
    for (int j = 0; j < 8; ++j) {
        float o = (x[j] - mu) * inv * g[lane + 64 * j] + bb[lane + 64 * j];
        unsigned short ob = bf16_bits(o);
        hp[lane + 64 * j] = ob;
        if (doFinal) facc += bits_to_f32(ob) * Wf[lane + 64 * j];
    }
    if (doFinal) {
        for (int off = 32; off; off >>= 1) facc += __shfl_xor(facc, off);
        if (lane == 0) out[row >> 12] = facc + bf[0];
    }
}

extern "C" void kernel_launch(void* const* d_in, const int* in_sizes, int n_in,
                              void* d_out, int out_size, void* d_ws, size_t ws_size,
                              hipStream_t stream) {
    (void)in_sizes; (void)n_in; (void)out_size; (void)ws_size;
    const float* x   = (const float*)d_in[0];
    const float* We  = (const float*)d_in[1];
    const float* be  = (const float*)d_in[2];
    const float* cls = (const float*)d_in[3];
    const float* Wq  = (const float*)d_in[4];
    const float* bq  = (const float*)d_in[5];
    const float* Wk  = (const float*)d_in[6];
    const float* bk  = (const float*)d_in[7];
    const float* Wv  = (const float*)d_in[8];
    const float* bv  = (const float*)d_in[9];
    const float* Wo  = (const float*)d_in[10];
    const float* bo  = (const float*)d_in[11];
    const float* g1  = (const float*)d_in[12];
    const float* b1  = (const float*)d_in[13];
    const float* g2  = (const float*)d_in[14];
    const float* b2  = (const float*)d_in[15];
    const float* W1  = (const float*)d_in[16];
    const float* bf1 = (const float*)d_in[17];
    const float* W2  = (const float*)d_in[18];
    const float* bf2 = (const float*)d_in[19];
    const float* Wf  = (const float*)d_in[20];
    const float* bff = (const float*)d_in[21];
    float* out = (float*)d_out;

    float* ws = (float*)d_ws;
    const size_t NT = (size_t)B * LSEQ * D;  // 4,194,304
    float* aout = ws + NT;                    // [NT, 2NT)
    __hip_bfloat16* kbf    = (__hip_bfloat16*)(ws + NT);      // overlays aout
    __hip_bfloat16* q_bf   = (__hip_bfloat16*)(ws + 2 * NT);  // NT bf16
    __hip_bfloat16* y1_bf  = (__hip_bfloat16*)(ws + 2 * NT);  // overlays q post-attn
    __hip_bfloat16* v_bf   = (__hip_bfloat16*)(ws + 4 * NT);
    __hip_bfloat16* h_bf   = (__hip_bfloat16*)(ws + 5 * NT);
    float* tmp  = ws;                         // [0, NT): W2 split-K partial (in-loop)
    float* Opart = ws + 3 * NT;
    float* msumb = Opart + (size_t)B * H * NS * U * 64;
    float* wpool = ws + 5 * NT + NT / 2;
    const size_t WPL = (size_t)4 * D * D + 2 * (size_t)DFF * D;  // bf16 elems/layer
    __hip_bfloat16* wpool_bf = (__hip_bfloat16*)wpool;           // 2 layers contiguous
    float* after_w = wpool + (2 * WPL) / 2;
    float* Mbuf = after_w;
    int* top    = (int*)(Mbuf + (size_t)B * H * LSEQ);
    float* vpart  = (float*)(top + B * H * U);
    float* baseb  = vpart + (size_t)128 * 64;
    unsigned long long* cand =
        (unsigned long long*)(((uintptr_t)(baseb + (size_t)B * D) + 7) & ~(uintptr_t)7);
    float* qkvbias = (float*)(cand + (size_t)B * H * 16 * U);          // 2 x 1536 floats
    unsigned char* flags = (unsigned char*)(qkvbias + 2 * 1536);       // B*LSEQ bytes

    const int ML = B * LSEQ;  // 8192
    const int CAST_N = 4 * (D * D / 4) + 2 * (DFF * D / 4);       // 786432
    dim3 gCast((CAST_N + 384 + 255) / 256, NL);

    // ---- pre-loop: dual-layer weight cast + fused embed(+posenc+cls) -> h_bf ----
    cast_weights_kernel<<<gCast, 256, 0, stream>>>(Wq, Wk, Wv, Wo, W1, W2, bq, bk, bv,
                                                   wpool_bf, qkvbias);
    embed_posenc_kernel<<<ML, 256, 0, stream>>>(x, We, be, cls, h_bf);

    for (int l = 0; l < NL; ++l) {
        // host-side threefry key schedule for this layer's sample indices
        uint32_t f0, f1, a0, a1, bb0, bb1;
        threefry_host(0u, 42u, 0u, (uint32_t)l, f0, f1);
        threefry_host(f0, f1, 0u, 2u, a0, a1);
        threefry_host(f0, f1, 1u, 3u, bb0, bb1);
        (void)a0; (void)bb0;

        __hip_bfloat16* wqb = wpool_bf + (size_t)l * WPL;  // wq|wk|wv packed
        __hip_bfloat16* wob = wqb + (size_t)3 * D * D;
        __hip_bfloat16* w1b = wqb + (size_t)4 * D * D;
        __hip_bfloat16* w2b = w1b + (size_t)DFF * D;

        // fused QKV GEMM: N=1536, 768 blocks, pipelined + XCD-swizzled (NBN=12)
        gemm_pipe<3><<<768, 256, 0, stream>>>((const unsigned short*)h_bf,
                                              (const unsigned short*)wqb,
                                              qkvbias + (size_t)l * 1536,
                                              q_bf, kbf, v_bf, ML, 3 * D, D, 12);

        mscore_kernel<<<B * LSEQ, 256, 0, stream>>>(q_bf, kbf, a1, bb1, Mbuf);
        topk_chunk_kernel<<<B * H * 16, 256, 0, stream>>>(Mbuf, cand);
        // fused: top-k merge ∥ vmean partial ∥ flag clear (16 + 128 + 8 blocks)
        topkmerge_vmean_kernel<<<B * H + B * H * 8 + 8, 256, 0, stream>>>(
            cand, top, v_bf, vpart, flags);
        attn_part<<<dim3(NS, H, B), 256, 0, stream>>>(q_bf, kbf, v_bf, top, Opart, msumb);
        // fused: zero corr rows ∥ wo_base with inline vm (720 + 256 blocks)
        zero_wobase_kernel<<<B * H * U + B * 128, 256, 0, stream>>>(
            top, aout, flags, vpart, (const unsigned short*)wob, bo + l * D, baseb);
        attnred_corr_kernel<<<B * H * U, 256, 0, stream>>>(Opart, msumb, vpart,
                                                           (const unsigned short*)wob, top,
                                                           aout);
        add_ln_base_kernel<<<ML, 64, 0, stream>>>(h_bf, baseb, aout, flags,
                                                  g1 + l * D, b1 + l * D);

        // W1: N=2048, 1024 blocks, pipelined + swizzled (NBN=16)
        gemm_pipe<2><<<1024, 256, 0, stream>>>((const unsigned short*)h_bf,
                                               (const unsigned short*)w1b, bf1 + l * DFF,
                                               y1_bf, nullptr, nullptr, ML, DFF, D, 16);
        // W2: m97-shape 128x128 BK=32 + split-K=2, 512 blocks; halves: aout(+bias)/tmp
        gemm_w2b<<<512, 256, 0, stream>>>((const unsigned short*)y1_bf,
                                          (const unsigned short*)w2b, bf2 + l * D,
                                          aout, tmp);
        // LN2 (+ fused final head on the last layer)
        add_ln_kernel<<<ML, 64, 0, stream>>>(h_bf, aout, tmp, g2 + l * D, b2 + l * D,
                                             Wf, bff, out, (l == NL - 1) ? 1 : 0);
    }
}

// Round 8
// 545.272 us; speedup vs baseline: 1.0831x; 1.0831x over previous
//
#include <hip/hip_runtime.h>
#include <hip/hip_bf16.h>
#include <math.h>
#include <stdint.h>

#define B 2
#define S 4095
#define LSEQ 4096
#define F_IN 32
#define D 512
#define H 8
#define E 64
#define DFF 2048
#define NL 2
#define U 45
#define EPSL 1e-5f
#define LU (LSEQ * U)
#define HALF_LU (LU / 2)
#define NS 32
#define SLICE 128

typedef __attribute__((ext_vector_type(8))) short short8;
typedef __attribute__((ext_vector_type(4))) float f32x4;

#define GLD(gp, lp)                                                            \
    __builtin_amdgcn_global_load_lds(                                          \
        (const __attribute__((address_space(1))) void*)(gp),                   \
        (__attribute__((address_space(3))) void*)(lp), 16, 0, 0)

__device__ __forceinline__ unsigned short bf16_bits(float f) {
    __hip_bfloat16 h = __float2bfloat16(f);
    return *(unsigned short*)&h;
}
__device__ __forceinline__ float bits_to_f32(unsigned short s) {
    union { uint32_t u; float f; } c;
    c.u = ((uint32_t)s) << 16;
    return c.f;
}
// monotone sortable key: desc key order == (value desc, index asc) — JAX top_k ties
__device__ __forceinline__ unsigned long long mkey(float v, int index) {
    uint32_t u = __float_as_uint(v);
    uint32_t mono = (u & 0x80000000u) ? ~u : (u | 0x80000000u);
    return ((unsigned long long)mono << 32) | (uint32_t)(0xFFFFFFFFu - (uint32_t)index);
}

// ---------------- Threefry-2x32 (20 rounds), exactly JAX's algorithm ----------------
#define TF_BODY(k0, k1, c0, c1, o0, o1)                                        \
    do {                                                                       \
        uint32_t ks2 = (k0) ^ (k1) ^ 0x1BD11BDAu;                              \
        uint32_t x0 = (c0) + (k0), x1 = (c1) + (k1);                           \
        x0 += x1; x1 = ((x1 << 13) | (x1 >> 19)); x1 ^= x0;                    \
        x0 += x1; x1 = ((x1 << 15) | (x1 >> 17)); x1 ^= x0;                    \
        x0 += x1; x1 = ((x1 << 26) | (x1 >> 6));  x1 ^= x0;                    \
        x0 += x1; x1 = ((x1 << 6) | (x1 >> 26));  x1 ^= x0;                    \
        x0 += (k1); x1 += ks2 + 1u;                                            \
        x0 += x1; x1 = ((x1 << 17) | (x1 >> 15)); x1 ^= x0;                    \
        x0 += x1; x1 = ((x1 << 29) | (x1 >> 3));  x1 ^= x0;                    \
        x0 += x1; x1 = ((x1 << 16) | (x1 >> 16)); x1 ^= x0;                    \
        x0 += x1; x1 = ((x1 << 24) | (x1 >> 8));  x1 ^= x0;                    \
        x0 += ks2; x1 += (k0) + 2u;                                            \
        x0 += x1; x1 = ((x1 << 13) | (x1 >> 19)); x1 ^= x0;                    \
        x0 += x1; x1 = ((x1 << 15) | (x1 >> 17)); x1 ^= x0;                    \
        x0 += x1; x1 = ((x1 << 26) | (x1 >> 6));  x1 ^= x0;                    \
        x0 += x1; x1 = ((x1 << 6) | (x1 >> 26));  x1 ^= x0;                    \
        x0 += (k0); x1 += (k1) + 3u;                                           \
        x0 += x1; x1 = ((x1 << 17) | (x1 >> 15)); x1 ^= x0;                    \
        x0 += x1; x1 = ((x1 << 29) | (x1 >> 3));  x1 ^= x0;                    \
        x0 += x1; x1 = ((x1 << 16) | (x1 >> 16)); x1 ^= x0;                    \
        x0 += x1; x1 = ((x1 << 24) | (x1 >> 8));  x1 ^= x0;                    \
        x0 += (k1); x1 += ks2 + 4u;                                            \
        x0 += x1; x1 = ((x1 << 13) | (x1 >> 19)); x1 ^= x0;                    \
        x0 += x1; x1 = ((x1 << 15) | (x1 >> 17)); x1 ^= x0;                    \
        x0 += x1; x1 = ((x1 << 26) | (x1 >> 6));  x1 ^= x0;                    \
        x0 += x1; x1 = ((x1 << 6) | (x1 >> 26));  x1 ^= x0;                    \
        x0 += ks2; x1 += (k0) + 5u;                                            \
        (o0) = x0; (o1) = x1;                                                  \
    } while (0)

__device__ __forceinline__ void threefry_dev(uint32_t k0, uint32_t k1, uint32_t c0,
                                             uint32_t c1, uint32_t& o0, uint32_t& o1) {
    TF_BODY(k0, k1, c0, c1, o0, o1);
}
static void threefry_host(uint32_t k0, uint32_t k1, uint32_t c0, uint32_t c1,
                          uint32_t& o0, uint32_t& o1) {
    TF_BODY(k0, k1, c0, c1, o0, o1);
}

// ------- prep: xbf[8192x32] (row l=0 zero, else x[b,l-1,:]) + We_bf cast -----------
// (Round-7 embed fusion REVERTED: per-output re-rounding of We cost 134M v_cvt ops
//  (32 per output vs 1 per weight) -> 66us VALU-bound. Fusions must conserve op
//  count, not just bytes. This 3-kernel path measured ~20us total in R6.)
__global__ void prep_embed_kernel(const float* __restrict__ x, const float* __restrict__ We,
                                  __hip_bfloat16* __restrict__ xbf,
                                  __hip_bfloat16* __restrict__ webf) {
    int u = blockIdx.x * blockDim.x + threadIdx.x;  // 4-element units
    const int NX = B * LSEQ * F_IN / 4;             // 65536
    const int NW = D * F_IN / 4;                    // 4096
    if (u < NX) {
        int e0 = u * 4;
        int i = e0 & 31;
        int l = (e0 >> 5) & (LSEQ - 1);
        int b = e0 >> 17;
        union { unsigned short s[4]; uint2 w; } o;
        if (l == 0) {
            o.s[0] = o.s[1] = o.s[2] = o.s[3] = 0;
        } else {
            float4 v = *(const float4*)(x + ((size_t)b * S + (l - 1)) * F_IN + i);
            o.s[0] = bf16_bits(v.x); o.s[1] = bf16_bits(v.y);
            o.s[2] = bf16_bits(v.z); o.s[3] = bf16_bits(v.w);
        }
        ((uint2*)xbf)[u] = o.w;
    } else if (u < NX + NW) {
        int w = u - NX;
        float4 v = ((const float4*)We)[w];
        union { unsigned short s[4]; uint2 w2; } o;
        o.s[0] = bf16_bits(v.x); o.s[1] = bf16_bits(v.y);
        o.s[2] = bf16_bits(v.z); o.s[3] = bf16_bits(v.w);
        ((uint2*)webf)[w] = o.w2;
    }
}

// ------- bf16 MFMA GEMM, BK=32, f32 out (embed) ------------------------------------
__global__ __launch_bounds__(256) void gemm32(const unsigned short* __restrict__ A,
                                              const unsigned short* __restrict__ W,
                                              const float* __restrict__ bias,
                                              float* __restrict__ Cf,
                                              int M, int N, int K) {
    __shared__ unsigned short lds[2 * 128 * 32];
    unsigned short* As = lds;
    unsigned short* Bs = lds + 128 * 32;
    const int tid = threadIdx.x;
    const int m0 = blockIdx.y * 128, n0 = blockIdx.x * 128;
    const int wave = tid >> 6, lane = tid & 63;
    const int wm = (wave >> 1) * 64, wn = (wave & 1) * 64;
    const int quad = lane >> 4, m15 = lane & 15;
    const int srow = tid >> 2, scol = (tid & 3) * 8;
    f32x4 acc[4][4] = {};
    const unsigned short* Ag0 = A + (size_t)(m0 + srow) * K + scol;
    const unsigned short* Ag1 = A + (size_t)(m0 + srow + 64) * K + scol;
    const unsigned short* Wg0 = W + (size_t)(n0 + srow) * K + scol;
    const unsigned short* Wg1 = W + (size_t)(n0 + srow + 64) * K + scol;
    for (int k0 = 0; k0 < K; k0 += 32) {
        __syncthreads();
        GLD(Ag0 + k0, As + tid * 8);
        GLD(Ag1 + k0, As + 2048 + tid * 8);
        GLD(Wg0 + k0, Bs + tid * 8);
        GLD(Wg1 + k0, Bs + 2048 + tid * 8);
        __syncthreads();
        short8 af[4], bfr[4];
#pragma unroll
        for (int mi = 0; mi < 4; ++mi)
            af[mi] = *(const short8*)(As + (wm + mi * 16 + m15) * 32 + quad * 8);
#pragma unroll
        for (int ni = 0; ni < 4; ++ni)
            bfr[ni] = *(const short8*)(Bs + (wn + ni * 16 + m15) * 32 + quad * 8);
#pragma unroll
        for (int mi = 0; mi < 4; ++mi)
#pragma unroll
            for (int ni = 0; ni < 4; ++ni)
                acc[mi][ni] = __builtin_amdgcn_mfma_f32_16x16x32_bf16(
                    af[mi], bfr[ni], acc[mi][ni], 0, 0, 0);
    }
#pragma unroll
    for (int mi = 0; mi < 4; ++mi) {
        int mg = m0 + wm + mi * 16 + quad * 4;
#pragma unroll
        for (int ni = 0; ni < 4; ++ni) {
            int ng = n0 + wn + ni * 16 + m15;
            float bv = bias[ng];
#pragma unroll
            for (int r = 0; r < 4; ++r)
                Cf[(size_t)(mg + r) * N + ng] = acc[mi][ni][r] + bv;
        }
    }
}

// ------- posenc: h_bf = bf16((l==0 ? cls : emb) + PE) ------------------------------
__global__ void posenc_kernel(const float* __restrict__ emb, const float* __restrict__ cls,
                              __hip_bfloat16* __restrict__ hbf) {
    int gid = blockIdx.x * blockDim.x + threadIdx.x;
    if (gid >= B * LSEQ * D) return;
    int d = gid % D;
    int l = (gid / D) % LSEQ;
    float v = (l == 0) ? cls[d] : emb[gid];
    int i = d >> 1;
    float divv = expf((float)(2 * i) * (float)(-9.210340371976184 / 512.0));
    float ang = (float)l * divv;
    v += (d & 1) ? cosf(ang) : sinf(ang);
    hbf[gid] = __float2bfloat16(v);
}

// ------- dual-layer weight cast + packed qkv bias (pre-loop, blockIdx.y = layer) ---
__global__ void cast_weights_kernel(const float* __restrict__ Wq,
                                    const float* __restrict__ Wk,
                                    const float* __restrict__ Wv,
                                    const float* __restrict__ Wo,
                                    const float* __restrict__ W1,
                                    const float* __restrict__ W2,
                                    const float* __restrict__ bq,
                                    const float* __restrict__ bk,
                                    const float* __restrict__ bv,
                                    __hip_bfloat16* __restrict__ wpool,
                                    float* __restrict__ qkvbias) {
    const int SDD = D * D / 4;       // 65536
    const int SFD = DFF * D / 4;     // 262144
    const int CAST_N = 4 * SDD + 2 * SFD;
    const size_t WPL = (size_t)4 * D * D + 2 * (size_t)DFF * D;  // bf16 elems/layer
    int l = blockIdx.y;
    int u = blockIdx.x * blockDim.x + threadIdx.x;
    __hip_bfloat16* base = wpool + (size_t)l * WPL;
    if (u >= CAST_N) {
        int j = u - CAST_N;
        if (j < 384) {               // packed qkv bias, 4-float units over 1536
            int seg = (j * 4) >> 9;  // 0:q 1:k 2:v
            int off = (j * 4) & 511;
            const float* src = (seg == 0) ? bq + l * D
                             : (seg == 1) ? bk + l * D : bv + l * D;
            *(float4*)(qkvbias + l * 1536 + j * 4) = *(const float4*)(src + off);
        }
        return;
    }
    const float* src;
    __hip_bfloat16* dst;
    int off;
    if (u < SDD)            { src = Wq + (size_t)l * D * D;   dst = base;                       off = u; }
    else if (u < 2 * SDD)   { src = Wk + (size_t)l * D * D;   dst = base + (size_t)D * D;       off = u - SDD; }
    else if (u < 3 * SDD)   { src = Wv + (size_t)l * D * D;   dst = base + (size_t)2 * D * D;   off = u - 2 * SDD; }
    else if (u < 4 * SDD)   { src = Wo + (size_t)l * D * D;   dst = base + (size_t)3 * D * D;   off = u - 3 * SDD; }
    else if (u < 4 * SDD + SFD) { src = W1 + (size_t)l * DFF * D; dst = base + (size_t)4 * D * D; off = u - 4 * SDD; }
    else { src = W2 + (size_t)l * D * DFF; dst = base + (size_t)4 * D * D + (size_t)DFF * D; off = u - 4 * SDD - SFD; }
    float4 v = ((const float4*)src)[off];
    union { unsigned short s[4]; uint2 w; } o;
    o.s[0] = bf16_bits(v.x); o.s[1] = bf16_bits(v.y);
    o.s[2] = bf16_bits(v.z); o.s[3] = bf16_bits(v.w);
    ((uint2*)dst)[off] = o.w;
}

// ------- PIPELINED bf16 MFMA GEMM, 128x128 tile, BK=32, dbuf, XCD-swizzled ---------
// MODE 1: bf16 out; 2: relu->bf16; 3: QKV (all three outputs bf16, segments of 512)
template <int MODE>
__global__ __launch_bounds__(256) void gemm_pipe(const unsigned short* __restrict__ A,
                                                 const unsigned short* __restrict__ W,
                                                 const float* __restrict__ bias,
                                                 void* __restrict__ C0,
                                                 void* __restrict__ C1,
                                                 void* __restrict__ C2,
                                                 int M, int N, int K, int NBN) {
    __shared__ unsigned short As[2][128 * 32];
    __shared__ unsigned short Bs[2][128 * 32];
    const int tid = threadIdx.x;
    const int NBM = M >> 7;
    const int bid = blockIdx.x;
    const int xcd = bid & 7, local = bid >> 3;
    const int m_t = xcd * (NBM >> 3) + local / NBN;
    const int n_t = local % NBN;
    const int m0 = m_t * 128, n0 = n_t * 128;
    const int wave = tid >> 6, lane = tid & 63;
    const int wm = (wave >> 1) * 64, wn = (wave & 1) * 64;
    const int quad = lane >> 4, m15 = lane & 15;
    const int srow = tid >> 2, scol = (tid & 3) * 8;
    f32x4 acc[4][4] = {};
    const unsigned short* Ag0 = A + (size_t)(m0 + srow) * K + scol;
    const unsigned short* Ag1 = A + (size_t)(m0 + srow + 64) * K + scol;
    const unsigned short* Wg0 = W + (size_t)(n0 + srow) * K + scol;
    const unsigned short* Wg1 = W + (size_t)(n0 + srow + 64) * K + scol;
    GLD(Ag0, As[0] + tid * 8);
    GLD(Ag1, As[0] + 2048 + tid * 8);
    GLD(Wg0, Bs[0] + tid * 8);
    GLD(Wg1, Bs[0] + 2048 + tid * 8);
    int cur = 0;
    for (int k0 = 0; k0 < K; k0 += 32) {
        __syncthreads();
        int kn = k0 + 32;
        if (kn < K) {
            GLD(Ag0 + kn, As[cur ^ 1] + tid * 8);
            GLD(Ag1 + kn, As[cur ^ 1] + 2048 + tid * 8);
            GLD(Wg0 + kn, Bs[cur ^ 1] + tid * 8);
            GLD(Wg1 + kn, Bs[cur ^ 1] + 2048 + tid * 8);
        }
        short8 af[4], bfr[4];
#pragma unroll
        for (int mi = 0; mi < 4; ++mi)
            af[mi] = *(const short8*)(As[cur] + (wm + mi * 16 + m15) * 32 + quad * 8);
#pragma unroll
        for (int ni = 0; ni < 4; ++ni)
            bfr[ni] = *(const short8*)(Bs[cur] + (wn + ni * 16 + m15) * 32 + quad * 8);
#pragma unroll
        for (int mi = 0; mi < 4; ++mi)
#pragma unroll
            for (int ni = 0; ni < 4; ++ni)
                acc[mi][ni] = __builtin_amdgcn_mfma_f32_16x16x32_bf16(
                    af[mi], bfr[ni], acc[mi][ni], 0, 0, 0);
        cur ^= 1;
    }
#pragma unroll
    for (int mi = 0; mi < 4; ++mi) {
        int mg = m0 + wm + mi * 16 + quad * 4;
#pragma unroll
        for (int ni = 0; ni < 4; ++ni) {
            int ng = n0 + wn + ni * 16 + m15;
            float bv = bias[ng];
#pragma unroll
            for (int r = 0; r < 4; ++r) {
                float v = acc[mi][ni][r] + bv;
                if (MODE == 1) {
                    ((__hip_bfloat16*)C0)[(size_t)(mg + r) * N + ng] = __float2bfloat16(v);
                } else if (MODE == 2) {
                    ((__hip_bfloat16*)C0)[(size_t)(mg + r) * N + ng] =
                        __float2bfloat16(fmaxf(v, 0.f));
                } else {  // QKV: N=1536, segments of 512, all bf16
                    int seg = ng >> 9;
                    int col = ng & 511;
                    __hip_bfloat16* dst = (seg == 0) ? (__hip_bfloat16*)C0
                                        : (seg == 1) ? (__hip_bfloat16*)C1
                                                     : (__hip_bfloat16*)C2;
                    dst[(size_t)(mg + r) * D + col] = __float2bfloat16(v);
                }
            }
        }
    }
}

// ------- W2 GEMM: m97-shape 128x128 BK=32 pipelined + split-K=2, f32 out -----------
__global__ __launch_bounds__(256) void gemm_w2b(const unsigned short* __restrict__ A,
                                                const unsigned short* __restrict__ W,
                                                const float* __restrict__ bias,
                                                float* __restrict__ C0,
                                                float* __restrict__ C1) {
    const int K = 2048, N = 512, KH = 1024;
    __shared__ unsigned short As[2][128 * 32];
    __shared__ unsigned short Bs[2][128 * 32];
    const int tid = threadIdx.x;
    const int bid = blockIdx.x;
    const int xcd = bid & 7, local = bid >> 3;
    const int m_t = xcd * 8 + (local >> 3);
    const int n_t = (local >> 1) & 3;
    const int ks = local & 1;
    const int m0 = m_t * 128, n0 = n_t * 128, kb = ks * KH;
    const int wave = tid >> 6, lane = tid & 63;
    const int wm = (wave >> 1) * 64, wn = (wave & 1) * 64;
    const int quad = lane >> 4, m15 = lane & 15;
    const int srow = tid >> 2, scol = (tid & 3) * 8;
    f32x4 acc[4][4] = {};
    const unsigned short* Ag0 = A + (size_t)(m0 + srow) * K + kb + scol;
    const unsigned short* Ag1 = A + (size_t)(m0 + srow + 64) * K + kb + scol;
    const unsigned short* Wg0 = W + (size_t)(n0 + srow) * K + kb + scol;
    const unsigned short* Wg1 = W + (size_t)(n0 + srow + 64) * K + kb + scol;
    GLD(Ag0, As[0] + tid * 8);
    GLD(Ag1, As[0] + 2048 + tid * 8);
    GLD(Wg0, Bs[0] + tid * 8);
    GLD(Wg1, Bs[0] + 2048 + tid * 8);
    int cur = 0;
    for (int k0 = 0; k0 < KH; k0 += 32) {
        __syncthreads();
        int kn = k0 + 32;
        if (kn < KH) {
            GLD(Ag0 + kn, As[cur ^ 1] + tid * 8);
            GLD(Ag1 + kn, As[cur ^ 1] + 2048 + tid * 8);
            GLD(Wg0 + kn, Bs[cur ^ 1] + tid * 8);
            GLD(Wg1 + kn, Bs[cur ^ 1] + 2048 + tid * 8);
        }
        short8 af[4], bfr[4];
#pragma unroll
        for (int mi = 0; mi < 4; ++mi)
            af[mi] = *(const short8*)(As[cur] + (wm + mi * 16 + m15) * 32 + quad * 8);
#pragma unroll
        for (int ni = 0; ni < 4; ++ni)
            bfr[ni] = *(const short8*)(Bs[cur] + (wn + ni * 16 + m15) * 32 + quad * 8);
#pragma unroll
        for (int mi = 0; mi < 4; ++mi)
#pragma unroll
            for (int ni = 0; ni < 4; ++ni)
                acc[mi][ni] = __builtin_amdgcn_mfma_f32_16x16x32_bf16(
                    af[mi], bfr[ni], acc[mi][ni], 0, 0, 0);
        cur ^= 1;
    }
    float* Cf = ks ? C1 : C0;
#pragma unroll
    for (int mi = 0; mi < 4; ++mi) {
        int mg = m0 + wm + mi * 16 + quad * 4;
#pragma unroll
        for (int ni = 0; ni < 4; ++ni) {
            int ng = n0 + wn + ni * 16 + m15;
            float bv = ks ? 0.f : bias[ng];
#pragma unroll
            for (int r = 0; r < 4; ++r)
                Cf[(size_t)(mg + r) * N + ng] = acc[mi][ni][r] + bv;
        }
    }
}

// -------- M-score: block per (b,l); 3-deep unrolled K-row gather -------------------
__global__ __launch_bounds__(256) void mscore_kernel(const __hip_bfloat16* __restrict__ qbf,
                                                     const __hip_bfloat16* __restrict__ kbf,
                                                     uint32_t k2a, uint32_t k2b,
                                                     float* __restrict__ Mv) {
    __shared__ float Sbuf[U][8];
    __shared__ int sidx[U];
    int bid = blockIdx.x;
    int b = bid & 1;
    int l = bid >> 1;
    int tid = threadIdx.x;
    int wave = tid >> 6, lane = tid & 63;
    if (tid < U) {
        int i = l * U + tid;
        uint32_t c0 = (i < HALF_LU) ? (uint32_t)i : (uint32_t)(i - HALF_LU);
        uint32_t o0, o1;
        threefry_dev(k2a, k2b, c0, c0 + HALF_LU, o0, o1);
        sidx[tid] = (int)(((i < HALF_LU) ? o0 : o1) & 4095u);
    }
    const unsigned short* qr =
        (const unsigned short*)qbf + ((size_t)(b * LSEQ) + l) * D + lane * 8;
    union { uint4 u; unsigned short s[8]; } qv;
    qv.u = *(const uint4*)qr;
    float qa[8];
#pragma unroll
    for (int j = 0; j < 8; ++j) qa[j] = bits_to_f32(qv.s[j]);
    __syncthreads();
    const unsigned short* kbase = (const unsigned short*)(kbf + (size_t)(b * LSEQ) * D);
    for (int t = wave; t < U; t += 12) {
        int tb = t + 4, tc = t + 8;
        bool hb = tb < U, hc = tc < U;
        union { uint4 u; unsigned short s[8]; } kva, kvb, kvc;
        kva.u = *(const uint4*)(kbase + (size_t)sidx[t] * D + lane * 8);
        if (hb) kvb.u = *(const uint4*)(kbase + (size_t)sidx[tb] * D + lane * 8);
        if (hc) kvc.u = *(const uint4*)(kbase + (size_t)sidx[tc] * D + lane * 8);
        {
            float p = 0.f;
#pragma unroll
            for (int j = 0; j < 8; ++j) p += qa[j] * bits_to_f32(kva.s[j]);
            p += __shfl_xor(p, 1);
            p += __shfl_xor(p, 2);
            p += __shfl_xor(p, 4);
            if ((lane & 7) == 0) Sbuf[t][lane >> 3] = p;
        }
        if (hb) {
            float p = 0.f;
#pragma unroll
            for (int j = 0; j < 8; ++j) p += qa[j] * bits_to_f32(kvb.s[j]);
            p += __shfl_xor(p, 1);
            p += __shfl_xor(p, 2);
            p += __shfl_xor(p, 4);
            if ((lane & 7) == 0) Sbuf[tb][lane >> 3] = p;
        }
        if (hc) {
            float p = 0.f;
#pragma unroll
            for (int j = 0; j < 8; ++j) p += qa[j] * bits_to_f32(kvc.s[j]);
            p += __shfl_xor(p, 1);
            p += __shfl_xor(p, 2);
            p += __shfl_xor(p, 4);
            if ((lane & 7) == 0) Sbuf[tc][lane >> 3] = p;
        }
    }
    __syncthreads();
    if (tid < 8) {
        float mx = -INFINITY, sm = 0.f;
        for (int t = 0; t < U; ++t) {
            float v = Sbuf[t][tid];
            mx = fmaxf(mx, v);
            sm += v;
        }
        Mv[((size_t)b * H + tid) * LSEQ + l] = mx - sm / (float)LSEQ;
    }
}

// ------- top-k phase A: bitonic sort each 256-chunk desc, emit top-45 keys ---------
__global__ __launch_bounds__(256) void topk_chunk_kernel(const float* __restrict__ Mv,
                                                         unsigned long long* __restrict__ cand) {
    __shared__ unsigned long long sk[256];
    int blk = blockIdx.x;  // B*H*16
    int chunk = blk & 15, bh = blk >> 4;
    int tid = threadIdx.x;
    int gi = chunk * 256 + tid;
    sk[tid] = mkey(Mv[(size_t)bh * LSEQ + gi], gi);
    __syncthreads();
    for (int k = 2; k <= 256; k <<= 1) {
        for (int j = k >> 1; j > 0; j >>= 1) {
            int ixj = tid ^ j;
            if (ixj > tid) {
                unsigned long long a = sk[tid], b = sk[ixj];
                bool desc = ((tid & k) == 0);
                if (desc ? (a < b) : (a > b)) { sk[tid] = b; sk[ixj] = a; }
            }
            __syncthreads();
        }
    }
    if (tid < U) cand[((size_t)bh * 16 + chunk) * U + tid] = sk[tid];
}

// ------- FUSED: top-k merge [0,16) ∥ vmean partial [16,144) ∥ flag clear [144,152) -
__global__ __launch_bounds__(256) void topkmerge_vmean_kernel(
        const unsigned long long* __restrict__ cand, int* __restrict__ top,
        const __hip_bfloat16* __restrict__ v, float* __restrict__ part,
        unsigned char* __restrict__ flags) {
    __shared__ unsigned long long sk[1024];
    __shared__ float red[4][64];
    int blk = blockIdx.x;
    int tid = threadIdx.x;
    if (blk < B * H) {  // ---- topk_merge role ----
        int bh = blk;
        for (int e = tid; e < 1024; e += 256)
            sk[e] = (e < 16 * U) ? cand[(size_t)bh * 16 * U + e] : 0ull;
        __syncthreads();
        for (int k = 2; k <= 1024; k <<= 1) {
            for (int j = k >> 1; j > 0; j >>= 1) {
                for (int e = tid; e < 1024; e += 256) {
                    int ixj = e ^ j;
                    if (ixj > e) {
                        unsigned long long a = sk[e], b = sk[ixj];
                        bool desc = ((e & k) == 0);
                        if (desc ? (a < b) : (a > b)) { sk[e] = b; sk[ixj] = a; }
                    }
                }
                __syncthreads();
            }
        }
        if (tid < U)
            top[bh * U + tid] = (int)(0xFFFFFFFFu - (uint32_t)(sk[tid] & 0xFFFFFFFFu));
    } else if (blk < B * H + B * H * 8) {  // ---- vmean_part role ----
        int vb = blk - B * H;  // 0..127
        int seg = vb & 7, hh = (vb >> 3) & 7, b = vb >> 6;
        int e = tid & 63, rg = tid >> 6;
        const __hip_bfloat16* vp =
            v + ((size_t)(b * LSEQ) + seg * 512) * D + hh * 64 + e;
        float acc = 0.f;
        for (int r = rg; r < 512; r += 4) acc += __bfloat162float(vp[(size_t)r * D]);
        red[rg][e] = acc;
        __syncthreads();
        if (tid < 64)
            part[(size_t)vb * 64 + tid] =
                red[0][tid] + red[1][tid] + red[2][tid] + red[3][tid];
    } else {  // ---- flag clear role: 8 blocks x 256 x 4B = 8192 B ----
        int fb = blk - (B * H + B * H * 8);
        ((int*)flags)[fb * 256 + tid] = 0;
    }
}

// ------- FUSED: zero selected aout rows (blocks [0,720)) ∥ wo_base (blocks [720,976))
__global__ __launch_bounds__(256) void zero_wobase_kernel(
        const int* __restrict__ top, float* __restrict__ aout,
        unsigned char* __restrict__ flags, const float* __restrict__ vpart,
        const unsigned short* __restrict__ wob, const float* __restrict__ bo,
        float* __restrict__ base) {
    int bid = blockIdx.x;
    int tid = threadIdx.x;
    if (bid < B * H * U) {  // ---- zero_corr role ----
        int t = bid % U;
        int bh = bid / U;
        int b = bh >> 3;
        int r = top[bh * U + t];
        if (tid < 128) {
            float4 z = {0.f, 0.f, 0.f, 0.f};
            ((float4*)(aout + (size_t)(b * LSEQ + r) * D))[tid] = z;
        }
        if (tid == 0) flags[b * LSEQ + r] = 1;
    } else {  // ---- wo_base role ----
        int wb = bid - B * H * U;           // 0..255
        int b = wb >> 7;
        int n = (wb & 127) * 4 + (tid >> 6);
        int lane = tid & 63;
        float vmv[8];
#pragma unroll
        for (int j = 0; j < 8; ++j) {
            int idx = lane * 8 + j;
            int hh = idx >> 6, e = idx & 63;
            float acc = 0.f;
#pragma unroll
            for (int s = 0; s < 8; ++s)
                acc += vpart[((size_t)(b * 8 + hh) * 8 + s) * 64 + e];
            vmv[j] = acc / (float)LSEQ;
        }
        union { uint4 u; unsigned short s[8]; } w;
        w.u = *(const uint4*)(wob + (size_t)n * D + lane * 8);
        float p = vmv[0] * bits_to_f32(w.s[0]) + vmv[1] * bits_to_f32(w.s[1]) +
                  vmv[2] * bits_to_f32(w.s[2]) + vmv[3] * bits_to_f32(w.s[3]) +
                  vmv[4] * bits_to_f32(w.s[4]) + vmv[5] * bits_to_f32(w.s[5]) +
                  vmv[6] * bits_to_f32(w.s[6]) + vmv[7] * bits_to_f32(w.s[7]);
        for (int off = 32; off; off >>= 1) p += __shfl_xor(p, off);
        if (lane == 0) base[(size_t)b * D + n] = p + bo[n];
    }
}

// ------- merged: combine slice partials -> dlt; scatter Wo correction --------------
__global__ __launch_bounds__(256) void attnred_corr_kernel(const float* __restrict__ Opart,
                                                           const float* __restrict__ msum,
                                                           const float* __restrict__ vpart,
                                                           const unsigned short* __restrict__ wob,
                                                           const int* __restrict__ top,
                                                           float* __restrict__ aout) {
    __shared__ float dlt[E];
    int bid = blockIdx.x;  // B*H*U
    int t = bid % U;
    int bh = bid / U;
    int b = bh >> 3, hh = bh & 7;
    int tid = threadIdx.x;
    if (tid < 64) {
        int lane = tid;
        float m_s = -INFINITY, ss = 0.f;
        if (lane < NS) {
            size_t base = (((size_t)bh * NS + lane) * U + t) * 2;
            m_s = msum[base];
            ss = msum[base + 1];
        }
        float M = m_s;
        for (int off = 32; off; off >>= 1) M = fmaxf(M, __shfl_xor(M, off));
        float e_s = (lane < NS) ? __expf(m_s - M) : 0.f;
        float d = ss * e_s;
        for (int off = 32; off; off >>= 1) d += __shfl_xor(d, off);
        float acc = 0.f;
        for (int s = 0; s < NS; ++s) {
            float w = __shfl(e_s, s);
            acc += w * Opart[(((size_t)bh * NS + s) * U + t) * 64 + lane];
        }
        float vmv = 0.f;
#pragma unroll
        for (int s = 0; s < 8; ++s) vmv += vpart[((size_t)bh * 8 + s) * 64 + lane];
        dlt[lane] = acc / d - vmv / (float)LSEQ;
    }
    __syncthreads();
    int r = top[bh * U + t];
    float* arow = aout + (size_t)(b * LSEQ + r) * D;
    for (int n = tid; n < D; n += 256) {
        const unsigned short* wr = wob + (size_t)n * D + hh * E;
        float acc = 0.f;
#pragma unroll
        for (int v4 = 0; v4 < 8; ++v4) {
            union { uint4 u; unsigned short s[8]; } w;
            w.u = *(const uint4*)(wr + v4 * 8);
#pragma unroll
            for (int j = 0; j < 8; ++j)
                acc += dlt[v4 * 8 + j] * bits_to_f32(w.s[j]);
        }
        atomicAdd(arow + n, acc);
    }
}

// -------- flash-style MFMA attention partial: block = (slice, h, b) ----------------
__global__ __launch_bounds__(256) void attn_part(const __hip_bfloat16* __restrict__ qbf,
                                                 const __hip_bfloat16* __restrict__ kbf,
                                                 const __hip_bfloat16* __restrict__ vbf,
                                                 const int* __restrict__ top,
                                                 float* __restrict__ Opart,
                                                 float* __restrict__ msum) {
    __shared__ unsigned short Qs[48 * 72];
    __shared__ unsigned short Ks[SLICE * 72];
    __shared__ unsigned short Vs[SLICE * 68];
    __shared__ unsigned short Ps[48 * 136];
    __shared__ float mred[48][4];
    __shared__ float sred[48][4];
    const int slice = blockIdx.x, hh = blockIdx.y, b = blockIdx.z;
    const int bh = b * H + hh;
    const int tid = threadIdx.x;
    const int s0 = slice * SLICE;
    for (int i = tid; i < 48 * 64; i += 256) {
        int t = i >> 6, e = i & 63;
        unsigned short v = 0;
        if (t < U) {
            int r = top[bh * U + t];
            v = ((const unsigned short*)qbf)[((size_t)(b * LSEQ) + r) * D + hh * E + e];
        }
        Qs[t * 72 + e] = v;
    }
    {
        const uint4* src = (const uint4*)(kbf + ((size_t)(b * LSEQ) + s0) * D + hh * E);
        for (int i = tid; i < SLICE * 8; i += 256) {
            int r = i >> 3, c = i & 7;
            uint4 d = src[(size_t)r * 64 + c];
            *(uint4*)(Ks + r * 72 + c * 8) = d;
        }
    }
    {
        const uint2* src = (const uint2*)(vbf + ((size_t)(b * LSEQ) + s0) * D + hh * E);
        for (int i = tid; i < SLICE * 16; i += 256) {
            int r = i >> 4, c = i & 15;
            uint2 d = src[(size_t)r * 128 + c];
            *(uint2*)(Vs + r * 68 + c * 4) = d;
        }
    }
    __syncthreads();
    const int wave = tid >> 6, lane = tid & 63;
    const int quad = lane >> 4, m15 = lane & 15;
    const int wc = wave * 32;
    f32x4 acc[3][2] = {};
#pragma unroll
    for (int ks = 0; ks < 2; ++ks) {
        short8 af[3], bfr[2];
#pragma unroll
        for (int mt = 0; mt < 3; ++mt)
            af[mt] = *(const short8*)(Qs + (mt * 16 + m15) * 72 + ks * 32 + quad * 8);
#pragma unroll
        for (int nt = 0; nt < 2; ++nt)
            bfr[nt] = *(const short8*)(Ks + (wc + nt * 16 + m15) * 72 + ks * 32 + quad * 8);
#pragma unroll
        for (int mt = 0; mt < 3; ++mt)
#pragma unroll
            for (int nt = 0; nt < 2; ++nt)
                acc[mt][nt] = __builtin_amdgcn_mfma_f32_16x16x32_bf16(
                    af[mt], bfr[nt], acc[mt][nt], 0, 0, 0);
    }
    float sc[3][2][4];
#pragma unroll
    for (int mt = 0; mt < 3; ++mt)
#pragma unroll
        for (int nt = 0; nt < 2; ++nt)
#pragma unroll
            for (int r = 0; r < 4; ++r) sc[mt][nt][r] = acc[mt][nt][r] * 0.125f;
#pragma unroll
    for (int mt = 0; mt < 3; ++mt)
#pragma unroll
        for (int r = 0; r < 4; ++r) {
            float mv = fmaxf(sc[mt][0][r], sc[mt][1][r]);
            mv = fmaxf(mv, __shfl_xor(mv, 1));
            mv = fmaxf(mv, __shfl_xor(mv, 2));
            mv = fmaxf(mv, __shfl_xor(mv, 4));
            mv = fmaxf(mv, __shfl_xor(mv, 8));
            if (m15 == 0) mred[mt * 16 + quad * 4 + r][wave] = mv;
        }
    __syncthreads();
#pragma unroll
    for (int mt = 0; mt < 3; ++mt)
#pragma unroll
        for (int r = 0; r < 4; ++r) {
            int row = mt * 16 + quad * 4 + r;
            float ms = fmaxf(fmaxf(mred[row][0], mred[row][1]),
                             fmaxf(mred[row][2], mred[row][3]));
            float p0 = __expf(sc[mt][0][r] - ms);
            float p1 = __expf(sc[mt][1][r] - ms);
            float sv = p0 + p1;
            sv += __shfl_xor(sv, 1);
            sv += __shfl_xor(sv, 2);
            sv += __shfl_xor(sv, 4);
            sv += __shfl_xor(sv, 8);
            if (m15 == 0) sred[row][wave] = sv;
            Ps[row * 136 + wc + m15] = bf16_bits(p0);
            Ps[row * 136 + wc + 16 + m15] = bf16_bits(p1);
        }
    __syncthreads();
    if (tid < U) {
        float mm = fmaxf(fmaxf(mred[tid][0], mred[tid][1]),
                         fmaxf(mred[tid][2], mred[tid][3]));
        float ss = sred[tid][0] + sred[tid][1] + sred[tid][2] + sred[tid][3];
        size_t base = (((size_t)bh * NS + slice) * U + tid) * 2;
        msum[base] = mm;
        msum[base + 1] = ss;
    }
    f32x4 apv[3] = {};
#pragma unroll
    for (int ks = 0; ks < 4; ++ks) {
        short8 bv;
#pragma unroll
        for (int j = 0; j < 8; ++j)
            bv[j] = (short)Vs[(ks * 32 + quad * 8 + j) * 68 + wave * 16 + m15];
        short8 af2[3];
#pragma unroll
        for (int mt = 0; mt < 3; ++mt)
            af2[mt] = *(const short8*)(Ps + (mt * 16 + m15) * 136 + ks * 32 + quad * 8);
#pragma unroll
        for (int mt = 0; mt < 3; ++mt)
            apv[mt] = __builtin_amdgcn_mfma_f32_16x16x32_bf16(af2[mt], bv, apv[mt], 0, 0, 0);
    }
    size_t obase = ((size_t)bh * NS + slice) * U;
#pragma unroll
    for (int mt = 0; mt < 3; ++mt)
#pragma unroll
        for (int r = 0; r < 4; ++r) {
            int row = mt * 16 + quad * 4 + r;
            if (row < U)
                Opart[(obase + row) * 64 + wave * 16 + m15] = apv[mt][r];
        }
}

// -------- LN1: hbf = LayerNorm(hbf + base[b] + sparse corr) * g + b (bf16 stream) --
__global__ __launch_bounds__(64) void add_ln_base_kernel(__hip_bfloat16* __restrict__ hbf,
                                                         const float* __restrict__ base,
                                                         const float* __restrict__ aout,
                                                         const unsigned char* __restrict__ flags,
                                                         const float* __restrict__ g,
                                                         const float* __restrict__ bb) {
    int row = blockIdx.x;
    int b = row >> 12;
    int lane = threadIdx.x;
    unsigned short* hp = (unsigned short*)hbf + (size_t)row * D;
    const float* bp = base + (size_t)b * D;
    const float* ap = aout + (size_t)row * D;
    bool has = flags[row] != 0;
    float x[8];
    float sum = 0.f;
#pragma unroll
    for (int j = 0; j < 8; ++j) {
        float a = bp[lane + 64 * j];
        if (has) a += ap[lane + 64 * j];
        x[j] = bits_to_f32(hp[lane + 64 * j]) + a;
        sum += x[j];
    }
    for (int off = 32; off; off >>= 1) sum += __shfl_xor(sum, off);
    float mu = sum / (float)D;
    float vs = 0.f;
#pragma unroll
    for (int j = 0; j < 8; ++j) {
        float dd = x[j] - mu;
        vs += dd * dd;
    }
    for (int off = 32; off; off >>= 1) vs += __shfl_xor(vs, off);
    float inv = 1.f / sqrtf(vs / (float)D + EPSL);
#pragma unroll
    for (int j = 0; j < 8; ++j) {
        float o = (x[j] - mu) * inv * g[lane + 64 * j] + bb[lane + 64 * j];
        hp[lane + 64 * j] = bf16_bits(o);
    }
}

// -------- LN2: hbf = LayerNorm(hbf + a + a2) * g + b; last layer fuses final head --
__global__ __launch_bounds__(64) void add_ln_kernel(__hip_bfloat16* __restrict__ hbf,
                                                    const float* __restrict__ a,
                                                    const float* __restrict__ a2,
                                                    const float* __restrict__ g,
                                                    const float* __restrict__ bb,
                                                    const float* __restrict__ Wf,
                                                    const float* __restrict__ bf,
                                                    float* __restrict__ out,
                                                    int fuseFinal) {
    int row = blockIdx.x;
    int lane = threadIdx.x;
    unsigned short* hp = (unsigned short*)hbf + (size_t)row * D;
    const float* ap = a + (size_t)row * D;
    const float* ap2 = a2 + (size_t)row * D;
    float x[8];
    float sum = 0.f;
#pragma unroll
    for (int j = 0; j < 8; ++j) {
        x[j] = bits_to_f32(hp[lane + 64 * j]) + ap[lane + 64 * j] + ap2[lane + 64 * j];
        sum += x[j];
    }
    for (int off = 32; off; off >>= 1) sum += __shfl_xor(sum, off);
    float mu = sum / (float)D;
    float vs = 0.f;
#pragma unroll
    for (int j = 0; j < 8; ++j) {
        float dd = x[j] - mu;
        vs += dd * dd;
    }
    for (int off = 32; off; off >>= 1) vs += __shfl_xor(vs, off);
    float inv = 1.f / sqrtf(vs / (float)D + EPSL);
    bool doFinal = fuseFinal && ((row & (LSEQ - 1)) == 0);
    float facc = 0.f;
#pragma unroll
    for (int j = 0; j < 8; ++j) {
        float o = (x[j] - mu) * inv * g[lane + 64 * j] + bb[lane + 64 * j];
        unsigned short ob = bf16_bits(o);
        hp[lane + 64 * j] = ob;
        if (doFinal) facc += bits_to_f32(ob) * Wf[lane + 64 * j];
    }
    if (doFinal) {
        for (int off = 32; off; off >>= 1) facc += __shfl_xor(facc, off);
        if (lane == 0) out[row >> 12] = facc + bf[0];
    }
}

extern "C" void kernel_launch(void* const* d_in, const int* in_sizes, int n_in,
                              void* d_out, int out_size, void* d_ws, size_t ws_size,
                              hipStream_t stream) {
    (void)in_sizes; (void)n_in; (void)out_size; (void)ws_size;
    const float* x   = (const float*)d_in[0];
    const float* We  = (const float*)d_in[1];
    const float* be  = (const float*)d_in[2];
    const float* cls = (const float*)d_in[3];
    const float* Wq  = (const float*)d_in[4];
    const float* bq  = (const float*)d_in[5];
    const float* Wk  = (const float*)d_in[6];
    const float* bk  = (const float*)d_in[7];
    const float* Wv  = (const float*)d_in[8];
    const float* bv  = (const float*)d_in[9];
    const float* Wo  = (const float*)d_in[10];
    const float* bo  = (const float*)d_in[11];
    const float* g1  = (const float*)d_in[12];
    const float* b1  = (const float*)d_in[13];
    const float* g2  = (const float*)d_in[14];
    const float* b2  = (const float*)d_in[15];
    const float* W1  = (const float*)d_in[16];
    const float* bf1 = (const float*)d_in[17];
    const float* W2  = (const float*)d_in[18];
    const float* bf2 = (const float*)d_in[19];
    const float* Wf  = (const float*)d_in[20];
    const float* bff = (const float*)d_in[21];
    float* out = (float*)d_out;

    float* ws = (float*)d_ws;
    const size_t NT = (size_t)B * LSEQ * D;  // 4,194,304
    float* aout = ws + NT;                    // [NT, 2NT)
    __hip_bfloat16* kbf    = (__hip_bfloat16*)(ws + NT);      // overlays aout
    __hip_bfloat16* q_bf   = (__hip_bfloat16*)(ws + 2 * NT);  // NT bf16
    __hip_bfloat16* y1_bf  = (__hip_bfloat16*)(ws + 2 * NT);  // overlays q post-attn
    __hip_bfloat16* v_bf   = (__hip_bfloat16*)(ws + 4 * NT);
    __hip_bfloat16* h_bf   = (__hip_bfloat16*)(ws + 5 * NT);
    float* emb  = ws;                         // [0, NT): pre-loop only
    float* tmp  = ws;                         // [0, NT): W2 split-K partial (in-loop)
    float* Opart = ws + 3 * NT;
    float* msumb = Opart + (size_t)B * H * NS * U * 64;
    float* wpool = ws + 5 * NT + NT / 2;
    const size_t WPL = (size_t)4 * D * D + 2 * (size_t)DFF * D;  // bf16 elems/layer
    __hip_bfloat16* wpool_bf = (__hip_bfloat16*)wpool;           // 2 layers contiguous
    float* after_w = wpool + (2 * WPL) / 2;
    float* Mbuf = after_w;
    int* top    = (int*)(Mbuf + (size_t)B * H * LSEQ);
    float* vpart  = (float*)(top + B * H * U);
    float* baseb  = vpart + (size_t)128 * 64;
    __hip_bfloat16* xbf  = (__hip_bfloat16*)(baseb + (size_t)B * D);   // B*LSEQ*F_IN
    __hip_bfloat16* webf = xbf + (size_t)B * LSEQ * F_IN;              // D*F_IN
    unsigned long long* cand =
        (unsigned long long*)(((uintptr_t)(webf + (size_t)D * F_IN) + 7) & ~(uintptr_t)7);
    float* qkvbias = (float*)(cand + (size_t)B * H * 16 * U);          // 2 x 1536 floats
    unsigned char* flags = (unsigned char*)(qkvbias + 2 * 1536);       // B*LSEQ bytes

    const int ML = B * LSEQ;  // 8192
    dim3 gD(D / 128, ML / 128);
    const int CAST_N = 4 * (D * D / 4) + 2 * (DFF * D / 4);       // 786432
    dim3 gCast((CAST_N + 384 + 255) / 256, NL);

    // ---- pre-loop: dual-layer cast; embed GEMM (f32) + posenc -> h_bf ----
    prep_embed_kernel<<<(B * LSEQ * F_IN / 4 + D * F_IN / 4 + 255) / 256, 256, 0, stream>>>(
        x, We, xbf, webf);
    cast_weights_kernel<<<gCast, 256, 0, stream>>>(Wq, Wk, Wv, Wo, W1, W2, bq, bk, bv,
                                                   wpool_bf, qkvbias);
    gemm32<<<gD, 256, 0, stream>>>((const unsigned short*)xbf,
                                   (const unsigned short*)webf, be, emb, ML, D, F_IN);
    posenc_kernel<<<(B * LSEQ * D + 255) / 256, 256, 0, stream>>>(emb, cls, h_bf);

    for (int l = 0; l < NL; ++l) {
        // host-side threefry key schedule for this layer's sample indices
        uint32_t f0, f1, a0, a1, bb0, bb1;
        threefry_host(0u, 42u, 0u, (uint32_t)l, f0, f1);
        threefry_host(f0, f1, 0u, 2u, a0, a1);
        threefry_host(f0, f1, 1u, 3u, bb0, bb1);
        (void)a0; (void)bb0;

        __hip_bfloat16* wqb = wpool_bf + (size_t)l * WPL;  // wq|wk|wv packed
        __hip_bfloat16* wob = wqb + (size_t)3 * D * D;
        __hip_bfloat16* w1b = wqb + (size_t)4 * D * D;
        __hip_bfloat16* w2b = w1b + (size_t)DFF * D;

        // fused QKV GEMM: N=1536, 768 blocks, pipelined + XCD-swizzled (NBN=12)
        gemm_pipe<3><<<768, 256, 0, stream>>>((const unsigned short*)h_bf,
                                              (const unsigned short*)wqb,
                                              qkvbias + (size_t)l * 1536,
                                              q_bf, kbf, v_bf, ML, 3 * D, D, 12);

        mscore_kernel<<<B * LSEQ, 256, 0, stream>>>(q_bf, kbf, a1, bb1, Mbuf);
        topk_chunk_kernel<<<B * H * 16, 256, 0, stream>>>(Mbuf, cand);
        // fused: top-k merge ∥ vmean partial ∥ flag clear (16 + 128 + 8 blocks)
        topkmerge_vmean_kernel<<<B * H + B * H * 8 + 8, 256, 0, stream>>>(
            cand, top, v_bf, vpart, flags);
        attn_part<<<dim3(NS, H, B), 256, 0, stream>>>(q_bf, kbf, v_bf, top, Opart, msumb);
        // fused: zero corr rows ∥ wo_base with inline vm (720 + 256 blocks)
        zero_wobase_kernel<<<B * H * U + B * 128, 256, 0, stream>>>(
            top, aout, flags, vpart, (const unsigned short*)wob, bo + l * D, baseb);
        attnred_corr_kernel<<<B * H * U, 256, 0, stream>>>(Opart, msumb, vpart,
                                                           (const unsigned short*)wob, top,
                                                           aout);
        add_ln_base_kernel<<<ML, 64, 0, stream>>>(h_bf, baseb, aout, flags,
                                                  g1 + l * D, b1 + l * D);

        // W1: N=2048, 1024 blocks, pipelined + swizzled (NBN=16)
        gemm_pipe<2><<<1024, 256, 0, stream>>>((const unsigned short*)h_bf,
                                               (const unsigned short*)w1b, bf1 + l * DFF,
                                               y1_bf, nullptr, nullptr, ML, DFF, D, 16);
        // W2: m97-shape 128x128 BK=32 + split-K=2, 512 blocks; halves: aout(+bias)/tmp
        gemm_w2b<<<512, 256, 0, stream>>>((const unsigned short*)y1_bf,
                                          (const unsigned short*)w2b, bf2 + l * D,
                                          aout, tmp);
        // LN2 (+ fused final head on the last layer)
        add_ln_kernel<<<ML, 64, 0, stream>>>(h_bf, aout, tmp, g2 + l * D, b2 + l * D,
                                             Wf, bff, out, (l == NL - 1) ? 1 : 0);
    }
}

// Round 9
// 541.795 us; speedup vs baseline: 1.0901x; 1.0064x over previous
//
#include <hip/hip_runtime.h>
#include <hip/hip_bf16.h>
#include <math.h>
#include <stdint.h>

#define B 2
#define S 4095
#define LSEQ 4096
#define F_IN 32
#define D 512
#define H 8
#define E 64
#define DFF 2048
#define NL 2
#define U 45
#define EPSL 1e-5f
#define LU (LSEQ * U)
#define HALF_LU (LU / 2)
#define NS 32
#define SLICE 128
#define CASTBLK 3074  // blocks per layer for the cast role ((CAST_N+384+255)/256)

typedef __attribute__((ext_vector_type(8))) short short8;
typedef __attribute__((ext_vector_type(4))) float f32x4;

#define GLD(gp, lp)                                                            \
    __builtin_amdgcn_global_load_lds(                                          \
        (const __attribute__((address_space(1))) void*)(gp),                   \
        (__attribute__((address_space(3))) void*)(lp), 16, 0, 0)

__device__ __forceinline__ unsigned short bf16_bits(float f) {
    __hip_bfloat16 h = __float2bfloat16(f);
    return *(unsigned short*)&h;
}
__device__ __forceinline__ float bits_to_f32(unsigned short s) {
    union { uint32_t u; float f; } c;
    c.u = ((uint32_t)s) << 16;
    return c.f;
}
// monotone sortable key: desc key order == (value desc, index asc) — JAX top_k ties
__device__ __forceinline__ unsigned long long mkey(float v, int index) {
    uint32_t u = __float_as_uint(v);
    uint32_t mono = (u & 0x80000000u) ? ~u : (u | 0x80000000u);
    return ((unsigned long long)mono << 32) | (uint32_t)(0xFFFFFFFFu - (uint32_t)index);
}

// ---------------- Threefry-2x32 (20 rounds), exactly JAX's algorithm ----------------
#define TF_BODY(k0, k1, c0, c1, o0, o1)                                        \
    do {                                                                       \
        uint32_t ks2 = (k0) ^ (k1) ^ 0x1BD11BDAu;                              \
        uint32_t x0 = (c0) + (k0), x1 = (c1) + (k1);                           \
        x0 += x1; x1 = ((x1 << 13) | (x1 >> 19)); x1 ^= x0;                    \
        x0 += x1; x1 = ((x1 << 15) | (x1 >> 17)); x1 ^= x0;                    \
        x0 += x1; x1 = ((x1 << 26) | (x1 >> 6));  x1 ^= x0;                    \
        x0 += x1; x1 = ((x1 << 6) | (x1 >> 26));  x1 ^= x0;                    \
        x0 += (k1); x1 += ks2 + 1u;                                            \
        x0 += x1; x1 = ((x1 << 17) | (x1 >> 15)); x1 ^= x0;                    \
        x0 += x1; x1 = ((x1 << 29) | (x1 >> 3));  x1 ^= x0;                    \
        x0 += x1; x1 = ((x1 << 16) | (x1 >> 16)); x1 ^= x0;                    \
        x0 += x1; x1 = ((x1 << 24) | (x1 >> 8));  x1 ^= x0;                    \
        x0 += ks2; x1 += (k0) + 2u;                                            \
        x0 += x1; x1 = ((x1 << 13) | (x1 >> 19)); x1 ^= x0;                    \
        x0 += x1; x1 = ((x1 << 15) | (x1 >> 17)); x1 ^= x0;                    \
        x0 += x1; x1 = ((x1 << 26) | (x1 >> 6));  x1 ^= x0;                    \
        x0 += x1; x1 = ((x1 << 6) | (x1 >> 26));  x1 ^= x0;                    \
        x0 += (k0); x1 += (k1) + 3u;                                           \
        x0 += x1; x1 = ((x1 << 17) | (x1 >> 15)); x1 ^= x0;                    \
        x0 += x1; x1 = ((x1 << 29) | (x1 >> 3));  x1 ^= x0;                    \
        x0 += x1; x1 = ((x1 << 16) | (x1 >> 16)); x1 ^= x0;                    \
        x0 += x1; x1 = ((x1 << 24) | (x1 >> 8));  x1 ^= x0;                    \
        x0 += (k1); x1 += ks2 + 4u;                                            \
        x0 += x1; x1 = ((x1 << 13) | (x1 >> 19)); x1 ^= x0;                    \
        x0 += x1; x1 = ((x1 << 15) | (x1 >> 17)); x1 ^= x0;                    \
        x0 += x1; x1 = ((x1 << 26) | (x1 >> 6));  x1 ^= x0;                    \
        x0 += x1; x1 = ((x1 << 6) | (x1 >> 26));  x1 ^= x0;                    \
        x0 += ks2; x1 += (k0) + 5u;                                            \
        (o0) = x0; (o1) = x1;                                                  \
    } while (0)

__device__ __forceinline__ void threefry_dev(uint32_t k0, uint32_t k1, uint32_t c0,
                                             uint32_t c1, uint32_t& o0, uint32_t& o1) {
    TF_BODY(k0, k1, c0, c1, o0, o1);
}
static void threefry_host(uint32_t k0, uint32_t k1, uint32_t c0, uint32_t c1,
                          uint32_t& o0, uint32_t& o1) {
    TF_BODY(k0, k1, c0, c1, o0, o1);
}

// ------- FUSED pre-loop: dual-layer weight cast [0,2*CASTBLK) ∥ embed prep ---------
// (prep_embed and cast_weights are independent elementwise passes — one dispatch.)
__global__ void prep_cast_kernel(const float* __restrict__ x, const float* __restrict__ We,
                                 __hip_bfloat16* __restrict__ xbf,
                                 __hip_bfloat16* __restrict__ webf,
                                 const float* __restrict__ Wq,
                                 const float* __restrict__ Wk,
                                 const float* __restrict__ Wv,
                                 const float* __restrict__ Wo,
                                 const float* __restrict__ W1,
                                 const float* __restrict__ W2,
                                 const float* __restrict__ bq,
                                 const float* __restrict__ bk,
                                 const float* __restrict__ bv,
                                 __hip_bfloat16* __restrict__ wpool,
                                 float* __restrict__ qkvbias) {
    const int SDD = D * D / 4;       // 65536
    const int SFD = DFF * D / 4;     // 262144
    const int CAST_N = 4 * SDD + 2 * SFD;
    const size_t WPL = (size_t)4 * D * D + 2 * (size_t)DFF * D;
    int bid = blockIdx.x;
    int tid = threadIdx.x;
    if (bid < 2 * CASTBLK) {  // ---- cast role ----
        int l = bid / CASTBLK;
        int u = (bid % CASTBLK) * 256 + tid;
        __hip_bfloat16* base = wpool + (size_t)l * WPL;
        if (u >= CAST_N) {
            int j = u - CAST_N;
            if (j < 384) {
                int seg = (j * 4) >> 9;
                int off = (j * 4) & 511;
                const float* src = (seg == 0) ? bq + l * D
                                 : (seg == 1) ? bk + l * D : bv + l * D;
                *(float4*)(qkvbias + l * 1536 + j * 4) = *(const float4*)(src + off);
            }
            return;
        }
        const float* src;
        __hip_bfloat16* dst;
        int off;
        if (u < SDD)            { src = Wq + (size_t)l * D * D;   dst = base;                       off = u; }
        else if (u < 2 * SDD)   { src = Wk + (size_t)l * D * D;   dst = base + (size_t)D * D;       off = u - SDD; }
        else if (u < 3 * SDD)   { src = Wv + (size_t)l * D * D;   dst = base + (size_t)2 * D * D;   off = u - 2 * SDD; }
        else if (u < 4 * SDD)   { src = Wo + (size_t)l * D * D;   dst = base + (size_t)3 * D * D;   off = u - 3 * SDD; }
        else if (u < 4 * SDD + SFD) { src = W1 + (size_t)l * DFF * D; dst = base + (size_t)4 * D * D; off = u - 4 * SDD; }
        else { src = W2 + (size_t)l * D * DFF; dst = base + (size_t)4 * D * D + (size_t)DFF * D; off = u - 4 * SDD - SFD; }
        float4 v = ((const float4*)src)[off];
        union { unsigned short s[4]; uint2 w; } o;
        o.s[0] = bf16_bits(v.x); o.s[1] = bf16_bits(v.y);
        o.s[2] = bf16_bits(v.z); o.s[3] = bf16_bits(v.w);
        ((uint2*)dst)[off] = o.w;
    } else {  // ---- prep role ----
        int u = (bid - 2 * CASTBLK) * 256 + tid;
        const int NX = B * LSEQ * F_IN / 4;  // 65536
        const int NW = D * F_IN / 4;         // 4096
        if (u < NX) {
            int e0 = u * 4;
            int i = e0 & 31;
            int l = (e0 >> 5) & (LSEQ - 1);
            int b = e0 >> 17;
            union { unsigned short s[4]; uint2 w; } o;
            if (l == 0) {
                o.s[0] = o.s[1] = o.s[2] = o.s[3] = 0;
            } else {
                float4 v = *(const float4*)(x + ((size_t)b * S + (l - 1)) * F_IN + i);
                o.s[0] = bf16_bits(v.x); o.s[1] = bf16_bits(v.y);
                o.s[2] = bf16_bits(v.z); o.s[3] = bf16_bits(v.w);
            }
            ((uint2*)xbf)[u] = o.w;
        } else if (u < NX + NW) {
            int w = u - NX;
            float4 v = ((const float4*)We)[w];
            union { unsigned short s[4]; uint2 w2; } o;
            o.s[0] = bf16_bits(v.x); o.s[1] = bf16_bits(v.y);
            o.s[2] = bf16_bits(v.z); o.s[3] = bf16_bits(v.w);
            ((uint2*)webf)[w] = o.w2;
        }
    }
}

// ------- bf16 MFMA GEMM, BK=32, f32 out (embed) ------------------------------------
__global__ __launch_bounds__(256) void gemm32(const unsigned short* __restrict__ A,
                                              const unsigned short* __restrict__ W,
                                              const float* __restrict__ bias,
                                              float* __restrict__ Cf,
                                              int M, int N, int K) {
    __shared__ unsigned short lds[2 * 128 * 32];
    unsigned short* As = lds;
    unsigned short* Bs = lds + 128 * 32;
    const int tid = threadIdx.x;
    const int m0 = blockIdx.y * 128, n0 = blockIdx.x * 128;
    const int wave = tid >> 6, lane = tid & 63;
    const int wm = (wave >> 1) * 64, wn = (wave & 1) * 64;
    const int quad = lane >> 4, m15 = lane & 15;
    const int srow = tid >> 2, scol = (tid & 3) * 8;
    f32x4 acc[4][4] = {};
    const unsigned short* Ag0 = A + (size_t)(m0 + srow) * K + scol;
    const unsigned short* Ag1 = A + (size_t)(m0 + srow + 64) * K + scol;
    const unsigned short* Wg0 = W + (size_t)(n0 + srow) * K + scol;
    const unsigned short* Wg1 = W + (size_t)(n0 + srow + 64) * K + scol;
    for (int k0 = 0; k0 < K; k0 += 32) {
        __syncthreads();
        GLD(Ag0 + k0, As + tid * 8);
        GLD(Ag1 + k0, As + 2048 + tid * 8);
        GLD(Wg0 + k0, Bs + tid * 8);
        GLD(Wg1 + k0, Bs + 2048 + tid * 8);
        __syncthreads();
        short8 af[4], bfr[4];
#pragma unroll
        for (int mi = 0; mi < 4; ++mi)
            af[mi] = *(const short8*)(As + (wm + mi * 16 + m15) * 32 + quad * 8);
#pragma unroll
        for (int ni = 0; ni < 4; ++ni)
            bfr[ni] = *(const short8*)(Bs + (wn + ni * 16 + m15) * 32 + quad * 8);
#pragma unroll
        for (int mi = 0; mi < 4; ++mi)
#pragma unroll
            for (int ni = 0; ni < 4; ++ni)
                acc[mi][ni] = __builtin_amdgcn_mfma_f32_16x16x32_bf16(
                    af[mi], bfr[ni], acc[mi][ni], 0, 0, 0);
    }
#pragma unroll
    for (int mi = 0; mi < 4; ++mi) {
        int mg = m0 + wm + mi * 16 + quad * 4;
#pragma unroll
        for (int ni = 0; ni < 4; ++ni) {
            int ng = n0 + wn + ni * 16 + m15;
            float bv = bias[ng];
#pragma unroll
            for (int r = 0; r < 4; ++r)
                Cf[(size_t)(mg + r) * N + ng] = acc[mi][ni][r] + bv;
        }
    }
}

// ------- posenc: h_bf = bf16((l==0 ? cls : emb) + PE) ------------------------------
__global__ void posenc_kernel(const float* __restrict__ emb, const float* __restrict__ cls,
                              __hip_bfloat16* __restrict__ hbf) {
    int gid = blockIdx.x * blockDim.x + threadIdx.x;
    if (gid >= B * LSEQ * D) return;
    int d = gid % D;
    int l = (gid / D) % LSEQ;
    float v = (l == 0) ? cls[d] : emb[gid];
    int i = d >> 1;
    float divv = expf((float)(2 * i) * (float)(-9.210340371976184 / 512.0));
    float ang = (float)l * divv;
    v += (d & 1) ? cosf(ang) : sinf(ang);
    hbf[gid] = __float2bfloat16(v);
}

// ------- PIPELINED bf16 MFMA GEMM, 128x128 tile, BK=32, dbuf, XCD-swizzled ---------
// MODE 1: bf16 out; 2: relu->bf16; 3: QKV (all three outputs bf16, segments of 512)
template <int MODE>
__global__ __launch_bounds__(256) void gemm_pipe(const unsigned short* __restrict__ A,
                                                 const unsigned short* __restrict__ W,
                                                 const float* __restrict__ bias,
                                                 void* __restrict__ C0,
                                                 void* __restrict__ C1,
                                                 void* __restrict__ C2,
                                                 int M, int N, int K, int NBN) {
    __shared__ unsigned short As[2][128 * 32];
    __shared__ unsigned short Bs[2][128 * 32];
    const int tid = threadIdx.x;
    const int NBM = M >> 7;
    const int bid = blockIdx.x;
    const int xcd = bid & 7, local = bid >> 3;
    const int m_t = xcd * (NBM >> 3) + local / NBN;
    const int n_t = local % NBN;
    const int m0 = m_t * 128, n0 = n_t * 128;
    const int wave = tid >> 6, lane = tid & 63;
    const int wm = (wave >> 1) * 64, wn = (wave & 1) * 64;
    const int quad = lane >> 4, m15 = lane & 15;
    const int srow = tid >> 2, scol = (tid & 3) * 8;
    f32x4 acc[4][4] = {};
    const unsigned short* Ag0 = A + (size_t)(m0 + srow) * K + scol;
    const unsigned short* Ag1 = A + (size_t)(m0 + srow + 64) * K + scol;
    const unsigned short* Wg0 = W + (size_t)(n0 + srow) * K + scol;
    const unsigned short* Wg1 = W + (size_t)(n0 + srow + 64) * K + scol;
    GLD(Ag0, As[0] + tid * 8);
    GLD(Ag1, As[0] + 2048 + tid * 8);
    GLD(Wg0, Bs[0] + tid * 8);
    GLD(Wg1, Bs[0] + 2048 + tid * 8);
    int cur = 0;
    for (int k0 = 0; k0 < K; k0 += 32) {
        __syncthreads();
        int kn = k0 + 32;
        if (kn < K) {
            GLD(Ag0 + kn, As[cur ^ 1] + tid * 8);
            GLD(Ag1 + kn, As[cur ^ 1] + 2048 + tid * 8);
            GLD(Wg0 + kn, Bs[cur ^ 1] + tid * 8);
            GLD(Wg1 + kn, Bs[cur ^ 1] + 2048 + tid * 8);
        }
        short8 af[4], bfr[4];
#pragma unroll
        for (int mi = 0; mi < 4; ++mi)
            af[mi] = *(const short8*)(As[cur] + (wm + mi * 16 + m15) * 32 + quad * 8);
#pragma unroll
        for (int ni = 0; ni < 4; ++ni)
            bfr[ni] = *(const short8*)(Bs[cur] + (wn + ni * 16 + m15) * 32 + quad * 8);
#pragma unroll
        for (int mi = 0; mi < 4; ++mi)
#pragma unroll
            for (int ni = 0; ni < 4; ++ni)
                acc[mi][ni] = __builtin_amdgcn_mfma_f32_16x16x32_bf16(
                    af[mi], bfr[ni], acc[mi][ni], 0, 0, 0);
        cur ^= 1;
    }
#pragma unroll
    for (int mi = 0; mi < 4; ++mi) {
        int mg = m0 + wm + mi * 16 + quad * 4;
#pragma unroll
        for (int ni = 0; ni < 4; ++ni) {
            int ng = n0 + wn + ni * 16 + m15;
            float bv = bias[ng];
#pragma unroll
            for (int r = 0; r < 4; ++r) {
                float v = acc[mi][ni][r] + bv;
                if (MODE == 1) {
                    ((__hip_bfloat16*)C0)[(size_t)(mg + r) * N + ng] = __float2bfloat16(v);
                } else if (MODE == 2) {
                    ((__hip_bfloat16*)C0)[(size_t)(mg + r) * N + ng] =
                        __float2bfloat16(fmaxf(v, 0.f));
                } else {  // QKV: N=1536, segments of 512, all bf16
                    int seg = ng >> 9;
                    int col = ng & 511;
                    __hip_bfloat16* dst = (seg == 0) ? (__hip_bfloat16*)C0
                                        : (seg == 1) ? (__hip_bfloat16*)C1
                                                     : (__hip_bfloat16*)C2;
                    dst[(size_t)(mg + r) * D + col] = __float2bfloat16(v);
                }
            }
        }
    }
}

// ------- W2 GEMM: m97-shape 128x128 BK=32 pipelined + split-K=2, f32 out -----------
__global__ __launch_bounds__(256) void gemm_w2b(const unsigned short* __restrict__ A,
                                                const unsigned short* __restrict__ W,
                                                const float* __restrict__ bias,
                                                float* __restrict__ C0,
                                                float* __restrict__ C1) {
    const int K = 2048, N = 512, KH = 1024;
    __shared__ unsigned short As[2][128 * 32];
    __shared__ unsigned short Bs[2][128 * 32];
    const int tid = threadIdx.x;
    const int bid = blockIdx.x;
    const int xcd = bid & 7, local = bid >> 3;
    const int m_t = xcd * 8 + (local >> 3);
    const int n_t = (local >> 1) & 3;
    const int ks = local & 1;
    const int m0 = m_t * 128, n0 = n_t * 128, kb = ks * KH;
    const int wave = tid >> 6, lane = tid & 63;
    const int wm = (wave >> 1) * 64, wn = (wave & 1) * 64;
    const int quad = lane >> 4, m15 = lane & 15;
    const int srow = tid >> 2, scol = (tid & 3) * 8;
    f32x4 acc[4][4] = {};
    const unsigned short* Ag0 = A + (size_t)(m0 + srow) * K + kb + scol;
    const unsigned short* Ag1 = A + (size_t)(m0 + srow + 64) * K + kb + scol;
    const unsigned short* Wg0 = W + (size_t)(n0 + srow) * K + kb + scol;
    const unsigned short* Wg1 = W + (size_t)(n0 + srow + 64) * K + kb + scol;
    GLD(Ag0, As[0] + tid * 8);
    GLD(Ag1, As[0] + 2048 + tid * 8);
    GLD(Wg0, Bs[0] + tid * 8);
    GLD(Wg1, Bs[0] + 2048 + tid * 8);
    int cur = 0;
    for (int k0 = 0; k0 < KH; k0 += 32) {
        __syncthreads();
        int kn = k0 + 32;
        if (kn < KH) {
            GLD(Ag0 + kn, As[cur ^ 1] + tid * 8);
            GLD(Ag1 + kn, As[cur ^ 1] + 2048 + tid * 8);
            GLD(Wg0 + kn, Bs[cur ^ 1] + tid * 8);
            GLD(Wg1 + kn, Bs[cur ^ 1] + 2048 + tid * 8);
        }
        short8 af[4], bfr[4];
#pragma unroll
        for (int mi = 0; mi < 4; ++mi)
            af[mi] = *(const short8*)(As[cur] + (wm + mi * 16 + m15) * 32 + quad * 8);
#pragma unroll
        for (int ni = 0; ni < 4; ++ni)
            bfr[ni] = *(const short8*)(Bs[cur] + (wn + ni * 16 + m15) * 32 + quad * 8);
#pragma unroll
        for (int mi = 0; mi < 4; ++mi)
#pragma unroll
            for (int ni = 0; ni < 4; ++ni)
                acc[mi][ni] = __builtin_amdgcn_mfma_f32_16x16x32_bf16(
                    af[mi], bfr[ni], acc[mi][ni], 0, 0, 0);
        cur ^= 1;
    }
    float* Cf = ks ? C1 : C0;
#pragma unroll
    for (int mi = 0; mi < 4; ++mi) {
        int mg = m0 + wm + mi * 16 + quad * 4;
#pragma unroll
        for (int ni = 0; ni < 4; ++ni) {
            int ng = n0 + wn + ni * 16 + m15;
            float bv = ks ? 0.f : bias[ng];
#pragma unroll
            for (int r = 0; r < 4; ++r)
                Cf[(size_t)(mg + r) * N + ng] = acc[mi][ni][r] + bv;
        }
    }
}

// -------- M-score [0,8192) ∥ acorr bulk clear [8192,8320) --------------------------
// (acorr no longer overlays kbf, so it can be cleared here — before `top` exists —
//  killing the separate zero_corr pass. 128 blocks x 256 thr x 32 float4 = 16MB.)
__global__ __launch_bounds__(256) void mscore_kernel(const __hip_bfloat16* __restrict__ qbf,
                                                     const __hip_bfloat16* __restrict__ kbf,
                                                     uint32_t k2a, uint32_t k2b,
                                                     float* __restrict__ Mv,
                                                     float* __restrict__ acorr) {
    __shared__ float Sbuf[U][8];
    __shared__ int sidx[U];
    int bid = blockIdx.x;
    int tid = threadIdx.x;
    if (bid >= B * LSEQ) {  // ---- acorr clear role ----
        int vb = bid - B * LSEQ;  // 0..127
        float4 z = {0.f, 0.f, 0.f, 0.f};
        float4* p = (float4*)acorr;
#pragma unroll
        for (int i = 0; i < 32; ++i)
            p[(size_t)i * 32768 + vb * 256 + tid] = z;
        return;
    }
    int b = bid & 1;
    int l = bid >> 1;
    int wave = tid >> 6, lane = tid & 63;
    if (tid < U) {
        int i = l * U + tid;
        uint32_t c0 = (i < HALF_LU) ? (uint32_t)i : (uint32_t)(i - HALF_LU);
        uint32_t o0, o1;
        threefry_dev(k2a, k2b, c0, c0 + HALF_LU, o0, o1);
        sidx[tid] = (int)(((i < HALF_LU) ? o0 : o1) & 4095u);
    }
    const unsigned short* qr =
        (const unsigned short*)qbf + ((size_t)(b * LSEQ) + l) * D + lane * 8;
    union { uint4 u; unsigned short s[8]; } qv;
    qv.u = *(const uint4*)qr;
    float qa[8];
#pragma unroll
    for (int j = 0; j < 8; ++j) qa[j] = bits_to_f32(qv.s[j]);
    __syncthreads();
    const unsigned short* kbase = (const unsigned short*)(kbf + (size_t)(b * LSEQ) * D);
    for (int t = wave; t < U; t += 12) {
        int tb = t + 4, tc = t + 8;
        bool hb = tb < U, hc = tc < U;
        union { uint4 u; unsigned short s[8]; } kva, kvb, kvc;
        kva.u = *(const uint4*)(kbase + (size_t)sidx[t] * D + lane * 8);
        if (hb) kvb.u = *(const uint4*)(kbase + (size_t)sidx[tb] * D + lane * 8);
        if (hc) kvc.u = *(const uint4*)(kbase + (size_t)sidx[tc] * D + lane * 8);
        {
            float p = 0.f;
#pragma unroll
            for (int j = 0; j < 8; ++j) p += qa[j] * bits_to_f32(kva.s[j]);
            p += __shfl_xor(p, 1);
            p += __shfl_xor(p, 2);
            p += __shfl_xor(p, 4);
            if ((lane & 7) == 0) Sbuf[t][lane >> 3] = p;
        }
        if (hb) {
            float p = 0.f;
#pragma unroll
            for (int j = 0; j < 8; ++j) p += qa[j] * bits_to_f32(kvb.s[j]);
            p += __shfl_xor(p, 1);
            p += __shfl_xor(p, 2);
            p += __shfl_xor(p, 4);
            if ((lane & 7) == 0) Sbuf[tb][lane >> 3] = p;
        }
        if (hc) {
            float p = 0.f;
#pragma unroll
            for (int j = 0; j < 8; ++j) p += qa[j] * bits_to_f32(kvc.s[j]);
            p += __shfl_xor(p, 1);
            p += __shfl_xor(p, 2);
            p += __shfl_xor(p, 4);
            if ((lane & 7) == 0) Sbuf[tc][lane >> 3] = p;
        }
    }
    __syncthreads();
    if (tid < 8) {
        float mx = -INFINITY, sm = 0.f;
        for (int t = 0; t < U; ++t) {
            float v = Sbuf[t][tid];
            mx = fmaxf(mx, v);
            sm += v;
        }
        Mv[((size_t)b * H + tid) * LSEQ + l] = mx - sm / (float)LSEQ;
    }
}

// ------- top-k phase A: bitonic sort each 256-chunk desc, emit top-45 keys ---------
__global__ __launch_bounds__(256) void topk_chunk_kernel(const float* __restrict__ Mv,
                                                         unsigned long long* __restrict__ cand) {
    __shared__ unsigned long long sk[256];
    int blk = blockIdx.x;  // B*H*16
    int chunk = blk & 15, bh = blk >> 4;
    int tid = threadIdx.x;
    int gi = chunk * 256 + tid;
    sk[tid] = mkey(Mv[(size_t)bh * LSEQ + gi], gi);
    __syncthreads();
    for (int k = 2; k <= 256; k <<= 1) {
        for (int j = k >> 1; j > 0; j >>= 1) {
            int ixj = tid ^ j;
            if (ixj > tid) {
                unsigned long long a = sk[tid], b = sk[ixj];
                bool desc = ((tid & k) == 0);
                if (desc ? (a < b) : (a > b)) { sk[tid] = b; sk[ixj] = a; }
            }
            __syncthreads();
        }
    }
    if (tid < U) cand[((size_t)bh * 16 + chunk) * U + tid] = sk[tid];
}

// ------- FUSED: top-k merge [0,16) ∥ vmean partial [16,144) ∥ flag clear [144,152) -
__global__ __launch_bounds__(256) void topkmerge_vmean_kernel(
        const unsigned long long* __restrict__ cand, int* __restrict__ top,
        const __hip_bfloat16* __restrict__ v, float* __restrict__ part,
        unsigned char* __restrict__ flags) {
    __shared__ unsigned long long sk[1024];
    __shared__ float red[4][64];
    int blk = blockIdx.x;
    int tid = threadIdx.x;
    if (blk < B * H) {  // ---- topk_merge role ----
        int bh = blk;
        for (int e = tid; e < 1024; e += 256)
            sk[e] = (e < 16 * U) ? cand[(size_t)bh * 16 * U + e] : 0ull;
        __syncthreads();
        for (int k = 2; k <= 1024; k <<= 1) {
            for (int j = k >> 1; j > 0; j >>= 1) {
                for (int e = tid; e < 1024; e += 256) {
                    int ixj = e ^ j;
                    if (ixj > e) {
                        unsigned long long a = sk[e], b = sk[ixj];
                        bool desc = ((e & k) == 0);
                        if (desc ? (a < b) : (a > b)) { sk[e] = b; sk[ixj] = a; }
                    }
                }
                __syncthreads();
            }
        }
        if (tid < U)
            top[bh * U + tid] = (int)(0xFFFFFFFFu - (uint32_t)(sk[tid] & 0xFFFFFFFFu));
    } else if (blk < B * H + B * H * 8) {  // ---- vmean_part role ----
        int vb = blk - B * H;  // 0..127
        int seg = vb & 7, hh = (vb >> 3) & 7, b = vb >> 6;
        int e = tid & 63, rg = tid >> 6;
        const __hip_bfloat16* vp =
            v + ((size_t)(b * LSEQ) + seg * 512) * D + hh * 64 + e;
        float acc = 0.f;
        for (int r = rg; r < 512; r += 4) acc += __bfloat162float(vp[(size_t)r * D]);
        red[rg][e] = acc;
        __syncthreads();
        if (tid < 64)
            part[(size_t)vb * 64 + tid] =
                red[0][tid] + red[1][tid] + red[2][tid] + red[3][tid];
    } else {  // ---- flag clear role: 8 blocks x 256 x 4B = 8192 B ----
        int fb = blk - (B * H + B * H * 8);
        ((int*)flags)[fb * 256 + tid] = 0;
    }
}

// ------- FUSED: attnred corr scatter [0,720) ∥ wo_base [720,976) -------------------
// (zero_corr pass eliminated: acorr was bulk-cleared in mscore; corr blocks
//  atomicAdd into acorr and set flags directly. wo_base role unchanged.)
__global__ __launch_bounds__(256) void attnred_wobase_kernel(
        const float* __restrict__ Opart, const float* __restrict__ msum,
        const float* __restrict__ vpart, const unsigned short* __restrict__ wob,
        const int* __restrict__ top, float* __restrict__ acorr,
        unsigned char* __restrict__ flags, const float* __restrict__ bo,
        float* __restrict__ base) {
    __shared__ float dlt[E];
    int bid = blockIdx.x;
    int tid = threadIdx.x;
    if (bid < B * H * U) {  // ---- attnred + scatter role ----
        int t = bid % U;
        int bh = bid / U;
        int b = bh >> 3, hh = bh & 7;
        if (tid < 64) {
            int lane = tid;
            float m_s = -INFINITY, ss = 0.f;
            if (lane < NS) {
                size_t base2 = (((size_t)bh * NS + lane) * U + t) * 2;
                m_s = msum[base2];
                ss = msum[base2 + 1];
            }
            float M = m_s;
            for (int off = 32; off; off >>= 1) M = fmaxf(M, __shfl_xor(M, off));
            float e_s = (lane < NS) ? __expf(m_s - M) : 0.f;
            float d = ss * e_s;
            for (int off = 32; off; off >>= 1) d += __shfl_xor(d, off);
            float acc = 0.f;
            for (int s = 0; s < NS; ++s) {
                float w = __shfl(e_s, s);
                acc += w * Opart[(((size_t)bh * NS + s) * U + t) * 64 + lane];
            }
            float vmv = 0.f;
#pragma unroll
            for (int s = 0; s < 8; ++s) vmv += vpart[((size_t)bh * 8 + s) * 64 + lane];
            dlt[lane] = acc / d - vmv / (float)LSEQ;
        }
        __syncthreads();
        int r = top[bh * U + t];
        if (tid == 0) flags[b * LSEQ + r] = 1;
        float* arow = acorr + (size_t)(b * LSEQ + r) * D;
        for (int n = tid; n < D; n += 256) {
            const unsigned short* wr = wob + (size_t)n * D + hh * E;
            float acc = 0.f;
#pragma unroll
            for (int v4 = 0; v4 < 8; ++v4) {
                union { uint4 u; unsigned short s[8]; } w;
                w.u = *(const uint4*)(wr + v4 * 8);
#pragma unroll
                for (int j = 0; j < 8; ++j)
                    acc += dlt[v4 * 8 + j] * bits_to_f32(w.s[j]);
            }
            atomicAdd(arow + n, acc);
        }
    } else {  // ---- wo_base role ----
        int wb = bid - B * H * U;           // 0..255
        int b = wb >> 7;
        int n = (wb & 127) * 4 + (tid >> 6);
        int lane = tid & 63;
        float vmv[8];
#pragma unroll
        for (int j = 0; j < 8; ++j) {
            int idx = lane * 8 + j;
            int hh = idx >> 6, e = idx & 63;
            float acc = 0.f;
#pragma unroll
            for (int s = 0; s < 8; ++s)
                acc += vpart[((size_t)(b * 8 + hh) * 8 + s) * 64 + e];
            vmv[j] = acc / (float)LSEQ;
        }
        union { uint4 u; unsigned short s[8]; } w;
        w.u = *(const uint4*)(wob + (size_t)n * D + lane * 8);
        float p = vmv[0] * bits_to_f32(w.s[0]) + vmv[1] * bits_to_f32(w.s[1]) +
                  vmv[2] * bits_to_f32(w.s[2]) + vmv[3] * bits_to_f32(w.s[3]) +
                  vmv[4] * bits_to_f32(w.s[4]) + vmv[5] * bits_to_f32(w.s[5]) +
                  vmv[6] * bits_to_f32(w.s[6]) + vmv[7] * bits_to_f32(w.s[7]);
        for (int off = 32; off; off >>= 1) p += __shfl_xor(p, off);
        if (lane == 0) base[(size_t)b * D + n] = p + bo[n];
    }
}

// -------- flash-style MFMA attention partial: block = (slice, h, b) ----------------
__global__ __launch_bounds__(256) void attn_part(const __hip_bfloat16* __restrict__ qbf,
                                                 const __hip_bfloat16* __restrict__ kbf,
                                                 const __hip_bfloat16* __restrict__ vbf,
                                                 const int* __restrict__ top,
                                                 float* __restrict__ Opart,
                                                 float* __restrict__ msum) {
    __shared__ unsigned short Qs[48 * 72];
    __shared__ unsigned short Ks[SLICE * 72];
    __shared__ unsigned short Vs[SLICE * 68];
    __shared__ unsigned short Ps[48 * 136];
    __shared__ float mred[48][4];
    __shared__ float sred[48][4];
    const int slice = blockIdx.x, hh = blockIdx.y, b = blockIdx.z;
    const int bh = b * H + hh;
    const int tid = threadIdx.x;
    const int s0 = slice * SLICE;
    for (int i = tid; i < 48 * 64; i += 256) {
        int t = i >> 6, e = i & 63;
        unsigned short v = 0;
        if (t < U) {
            int r = top[bh * U + t];
            v = ((const unsigned short*)qbf)[((size_t)(b * LSEQ) + r) * D + hh * E + e];
        }
        Qs[t * 72 + e] = v;
    }
    {
        const uint4* src = (const uint4*)(kbf + ((size_t)(b * LSEQ) + s0) * D + hh * E);
        for (int i = tid; i < SLICE * 8; i += 256) {
            int r = i >> 3, c = i & 7;
            uint4 d = src[(size_t)r * 64 + c];
            *(uint4*)(Ks + r * 72 + c * 8) = d;
        }
    }
    {
        const uint2* src = (const uint2*)(vbf + ((size_t)(b * LSEQ) + s0) * D + hh * E);
        for (int i = tid; i < SLICE * 16; i += 256) {
            int r = i >> 4, c = i & 15;
            uint2 d = src[(size_t)r * 128 + c];
            *(uint2*)(Vs + r * 68 + c * 4) = d;
        }
    }
    __syncthreads();
    const int wave = tid >> 6, lane = tid & 63;
    const int quad = lane >> 4, m15 = lane & 15;
    const int wc = wave * 32;
    f32x4 acc[3][2] = {};
#pragma unroll
    for (int ks = 0; ks < 2; ++ks) {
        short8 af[3], bfr[2];
#pragma unroll
        for (int mt = 0; mt < 3; ++mt)
            af[mt] = *(const short8*)(Qs + (mt * 16 + m15) * 72 + ks * 32 + quad * 8);
#pragma unroll
        for (int nt = 0; nt < 2; ++nt)
            bfr[nt] = *(const short8*)(Ks + (wc + nt * 16 + m15) * 72 + ks * 32 + quad * 8);
#pragma unroll
        for (int mt = 0; mt < 3; ++mt)
#pragma unroll
            for (int nt = 0; nt < 2; ++nt)
                acc[mt][nt] = __builtin_amdgcn_mfma_f32_16x16x32_bf16(
                    af[mt], bfr[nt], acc[mt][nt], 0, 0, 0);
    }
    float sc[3][2][4];
#pragma unroll
    for (int mt = 0; mt < 3; ++mt)
#pragma unroll
        for (int nt = 0; nt < 2; ++nt)
#pragma unroll
            for (int r = 0; r < 4; ++r) sc[mt][nt][r] = acc[mt][nt][r] * 0.125f;
#pragma unroll
    for (int mt = 0; mt < 3; ++mt)
#pragma unroll
        for (int r = 0; r < 4; ++r) {
            float mv = fmaxf(sc[mt][0][r], sc[mt][1][r]);
            mv = fmaxf(mv, __shfl_xor(mv, 1));
            mv = fmaxf(mv, __shfl_xor(mv, 2));
            mv = fmaxf(mv, __shfl_xor(mv, 4));
            mv = fmaxf(mv, __shfl_xor(mv, 8));
            if (m15 == 0) mred[mt * 16 + quad * 4 + r][wave] = mv;
        }
    __syncthreads();
#pragma unroll
    for (int mt = 0; mt < 3; ++mt)
#pragma unroll
        for (int r = 0; r < 4; ++r) {
            int row = mt * 16 + quad * 4 + r;
            float ms = fmaxf(fmaxf(mred[row][0], mred[row][1]),
                             fmaxf(mred[row][2], mred[row][3]));
            float p0 = __expf(sc[mt][0][r] - ms);
            float p1 = __expf(sc[mt][1][r] - ms);
            float sv = p0 + p1;
            sv += __shfl_xor(sv, 1);
            sv += __shfl_xor(sv, 2);
            sv += __shfl_xor(sv, 4);
            sv += __shfl_xor(sv, 8);
            if (m15 == 0) sred[row][wave] = sv;
            Ps[row * 136 + wc + m15] = bf16_bits(p0);
            Ps[row * 136 + wc + 16 + m15] = bf16_bits(p1);
        }
    __syncthreads();
    if (tid < U) {
        float mm = fmaxf(fmaxf(mred[tid][0], mred[tid][1]),
                         fmaxf(mred[tid][2], mred[tid][3]));
        float ss = sred[tid][0] + sred[tid][1] + sred[tid][2] + sred[tid][3];
        size_t base = (((size_t)bh * NS + slice) * U + tid) * 2;
        msum[base] = mm;
        msum[base + 1] = ss;
    }
    f32x4 apv[3] = {};
#pragma unroll
    for (int ks = 0; ks < 4; ++ks) {
        short8 bv;
#pragma unroll
        for (int j = 0; j < 8; ++j)
            bv[j] = (short)Vs[(ks * 32 + quad * 8 + j) * 68 + wave * 16 + m15];
        short8 af2[3];
#pragma unroll
        for (int mt = 0; mt < 3; ++mt)
            af2[mt] = *(const short8*)(Ps + (mt * 16 + m15) * 136 + ks * 32 + quad * 8);
#pragma unroll
        for (int mt = 0; mt < 3; ++mt)
            apv[mt] = __builtin_amdgcn_mfma_f32_16x16x32_bf16(af2[mt], bv, apv[mt], 0, 0, 0);
    }
    size_t obase = ((size_t)bh * NS + slice) * U;
#pragma unroll
    for (int mt = 0; mt < 3; ++mt)
#pragma unroll
        for (int r = 0; r < 4; ++r) {
            int row = mt * 16 + quad * 4 + r;
            if (row < U)
                Opart[(obase + row) * 64 + wave * 16 + m15] = apv[mt][r];
        }
}

// -------- LN1: hbf = LayerNorm(hbf + base[b] + sparse corr) * g + b (bf16 stream) --
__global__ __launch_bounds__(64) void add_ln_base_kernel(__hip_bfloat16* __restrict__ hbf,
                                                         const float* __restrict__ base,
                                                         const float* __restrict__ acorr,
                                                         const unsigned char* __restrict__ flags,
                                                         const float* __restrict__ g,
                                                         const float* __restrict__ bb) {
    int row = blockIdx.x;
    int b = row >> 12;
    int lane = threadIdx.x;
    unsigned short* hp = (unsigned short*)hbf + (size_t)row * D;
    const float* bp = base + (size_t)b * D;
    const float* ap = acorr + (size_t)row * D;
    bool has = flags[row] != 0;
    float x[8];
    float sum = 0.f;
#pragma unroll
    for (int j = 0; j < 8; ++j) {
        float a = bp[lane + 64 * j];
        if (has) a += ap[lane + 64 * j];
        x[j] = bits_to_f32(hp[lane + 64 * j]) + a;
        sum += x[j];
    }
    for (int off = 32; off; off >>= 1) sum += __shfl_xor(sum, off);
    float mu = sum / (float)D;
    float vs = 0.f;
#pragma unroll
    for (int j = 0; j < 8; ++j) {
        float dd = x[j] - mu;
        vs += dd * dd;
    }
    for (int off = 32; off; off >>= 1) vs += __shfl_xor(vs, off);
    float inv = 1.f / sqrtf(vs / (float)D + EPSL);
#pragma unroll
    for (int j = 0; j < 8; ++j) {
        float o = (x[j] - mu) * inv * g[lane + 64 * j] + bb[lane + 64 * j];
        hp[lane + 64 * j] = bf16_bits(o);
    }
}

// -------- LN2: hbf = LayerNorm(hbf + a + a2) * g + b; last layer fuses final head --
__global__ __launch_bounds__(64) void add_ln_kernel(__hip_bfloat16* __restrict__ hbf,
                                                    const float* __restrict__ a,
                                                    const float* __restrict__ a2,
                                                    const float* __restrict__ g,
                                                    const float* __restrict__ bb,
                                                    const float* __restrict__ Wf,
                                                    const float* __restrict__ bf,
                                                    float* __restrict__ out,
                                                    int fuseFinal) {
    int row = blockIdx.x;
    int lane = threadIdx.x;
    unsigned short* hp = (unsigned short*)hbf + (size_t)row * D;
    const float* ap = a + (size_t)row * D;
    const float* ap2 = a2 + (size_t)row * D;
    float x[8];
    float sum = 0.f;
#pragma unroll
    for (int j = 0; j < 8; ++j) {
        x[j] = bits_to_f32(hp[lane + 64 * j]) + ap[lane + 64 * j] + ap2[lane + 64 * j];
        sum += x[j];
    }
    for (int off = 32; off; off >>= 1) sum += __shfl_xor(sum, off);
    float mu = sum / (float)D;
    float vs = 0.f;
#pragma unroll
    for (int j = 0; j < 8; ++j) {
        float dd = x[j] - mu;
        vs += dd * dd;
    }
    for (int off = 32; off; off >>= 1) vs += __shfl_xor(vs, off);
    float inv = 1.f / sqrtf(vs / (float)D + EPSL);
    bool doFinal = fuseFinal && ((row & (LSEQ - 1)) == 0);
    float facc = 0.f;
#pragma unroll
    for (int j = 0; j < 8; ++j) {
        float o = (x[j] - mu) * inv * g[lane + 64 * j] + bb[lane + 64 * j];
        unsigned short ob = bf16_bits(o);
        hp[lane + 64 * j] = ob;
        if (doFinal) facc += bits_to_f32(ob) * Wf[lane + 64 * j];
    }
    if (doFinal) {
        for (int off = 32; off; off >>= 1) facc += __shfl_xor(facc, off);
        if (lane == 0) out[row >> 12] = facc + bf[0];
    }
}

extern "C" void kernel_launch(void* const* d_in, const int* in_sizes, int n_in,
                              void* d_out, int out_size, void* d_ws, size_t ws_size,
                              hipStream_t stream) {
    (void)in_sizes; (void)n_in; (void)out_size; (void)ws_size;
    const float* x   = (const float*)d_in[0];
    const float* We  = (const float*)d_in[1];
    const float* be  = (const float*)d_in[2];
    const float* cls = (const float*)d_in[3];
    const float* Wq  = (const float*)d_in[4];
    const float* bq  = (const float*)d_in[5];
    const float* Wk  = (const float*)d_in[6];
    const float* bk  = (const float*)d_in[7];
    const float* Wv  = (const float*)d_in[8];
    const float* bv  = (const float*)d_in[9];
    const float* Wo  = (const float*)d_in[10];
    const float* bo  = (const float*)d_in[11];
    const float* g1  = (const float*)d_in[12];
    const float* b1  = (const float*)d_in[13];
    const float* g2  = (const float*)d_in[14];
    const float* b2  = (const float*)d_in[15];
    const float* W1  = (const float*)d_in[16];
    const float* bf1 = (const float*)d_in[17];
    const float* W2  = (const float*)d_in[18];
    const float* bf2 = (const float*)d_in[19];
    const float* Wf  = (const float*)d_in[20];
    const float* bff = (const float*)d_in[21];
    float* out = (float*)d_out;

    float* ws = (float*)d_ws;
    const size_t NT = (size_t)B * LSEQ * D;  // 4,194,304
    float* aout = ws + NT;                    // [NT, 2NT): W2 ks0 output (kbf overlay)
    __hip_bfloat16* kbf    = (__hip_bfloat16*)(ws + NT);      // overlays aout
    __hip_bfloat16* q_bf   = (__hip_bfloat16*)(ws + 2 * NT);  // NT bf16
    __hip_bfloat16* y1_bf  = (__hip_bfloat16*)(ws + 2 * NT);  // overlays q post-attn
    __hip_bfloat16* v_bf   = (__hip_bfloat16*)(ws + 4 * NT);
    __hip_bfloat16* h_bf   = (__hip_bfloat16*)(ws + 5 * NT);
    float* emb   = ws;   // [0, NT): pre-loop only
    float* acorr = ws;   // [0, NT): in-loop sparse attn corrections (no kbf overlay!)
    float* tmp   = ws;   // [0, NT): W2 split-K partial (after add_ln_base consumed acorr)
    float* Opart = ws + 3 * NT;
    float* msumb = Opart + (size_t)B * H * NS * U * 64;
    float* wpool = ws + 5 * NT + NT / 2;
    const size_t WPL = (size_t)4 * D * D + 2 * (size_t)DFF * D;  // bf16 elems/layer
    __hip_bfloat16* wpool_bf = (__hip_bfloat16*)wpool;           // 2 layers contiguous
    float* after_w = wpool + (2 * WPL) / 2;
    float* Mbuf = after_w;
    int* top    = (int*)(Mbuf + (size_t)B * H * LSEQ);
    float* vpart  = (float*)(top + B * H * U);
    float* baseb  = vpart + (size_t)128 * 64;
    __hip_bfloat16* xbf  = (__hip_bfloat16*)(baseb + (size_t)B * D);   // B*LSEQ*F_IN
    __hip_bfloat16* webf = xbf + (size_t)B * LSEQ * F_IN;              // D*F_IN
    unsigned long long* cand =
        (unsigned long long*)(((uintptr_t)(webf + (size_t)D * F_IN) + 7) & ~(uintptr_t)7);
    float* qkvbias = (float*)(cand + (size_t)B * H * 16 * U);          // 2 x 1536 floats
    unsigned char* flags = (unsigned char*)(qkvbias + 2 * 1536);       // B*LSEQ bytes

    const int ML = B * LSEQ;  // 8192
    dim3 gD(D / 128, ML / 128);
    const int NPREP = (B * LSEQ * F_IN / 4 + D * F_IN / 4 + 255) / 256;  // 272

    // ---- pre-loop: merged (dual-layer cast ∥ embed prep); embed GEMM + posenc ----
    prep_cast_kernel<<<2 * CASTBLK + NPREP, 256, 0, stream>>>(
        x, We, xbf, webf, Wq, Wk, Wv, Wo, W1, W2, bq, bk, bv, wpool_bf, qkvbias);
    gemm32<<<gD, 256, 0, stream>>>((const unsigned short*)xbf,
                                   (const unsigned short*)webf, be, emb, ML, D, F_IN);
    posenc_kernel<<<(B * LSEQ * D + 255) / 256, 256, 0, stream>>>(emb, cls, h_bf);

    for (int l = 0; l < NL; ++l) {
        // host-side threefry key schedule for this layer's sample indices
        uint32_t f0, f1, a0, a1, bb0, bb1;
        threefry_host(0u, 42u, 0u, (uint32_t)l, f0, f1);
        threefry_host(f0, f1, 0u, 2u, a0, a1);
        threefry_host(f0, f1, 1u, 3u, bb0, bb1);
        (void)a0; (void)bb0;

        __hip_bfloat16* wqb = wpool_bf + (size_t)l * WPL;  // wq|wk|wv packed
        __hip_bfloat16* wob = wqb + (size_t)3 * D * D;
        __hip_bfloat16* w1b = wqb + (size_t)4 * D * D;
        __hip_bfloat16* w2b = w1b + (size_t)DFF * D;

        // fused QKV GEMM: N=1536, 768 blocks, pipelined + XCD-swizzled (NBN=12)
        gemm_pipe<3><<<768, 256, 0, stream>>>((const unsigned short*)h_bf,
                                              (const unsigned short*)wqb,
                                              qkvbias + (size_t)l * 1536,
                                              q_bf, kbf, v_bf, ML, 3 * D, D, 12);

        // mscore + acorr bulk clear (8192 + 128 blocks)
        mscore_kernel<<<B * LSEQ + 128, 256, 0, stream>>>(q_bf, kbf, a1, bb1, Mbuf,
                                                          acorr);
        topk_chunk_kernel<<<B * H * 16, 256, 0, stream>>>(Mbuf, cand);
        // fused: top-k merge ∥ vmean partial ∥ flag clear (16 + 128 + 8 blocks)
        topkmerge_vmean_kernel<<<B * H + B * H * 8 + 8, 256, 0, stream>>>(
            cand, top, v_bf, vpart, flags);
        attn_part<<<dim3(NS, H, B), 256, 0, stream>>>(q_bf, kbf, v_bf, top, Opart, msumb);
        // fused: attnred corr scatter (into pre-cleared acorr) ∥ wo_base (720+256)
        attnred_wobase_kernel<<<B * H * U + B * 128, 256, 0, stream>>>(
            Opart, msumb, vpart, (const unsigned short*)wob, top, acorr, flags,
            bo + l * D, baseb);
        add_ln_base_kernel<<<ML, 64, 0, stream>>>(h_bf, baseb, acorr, flags,
                                                  g1 + l * D, b1 + l * D);

        // W1: N=2048, 1024 blocks, pipelined + swizzled (NBN=16)
        gemm_pipe<2><<<1024, 256, 0, stream>>>((const unsigned short*)h_bf,
                                               (const unsigned short*)w1b, bf1 + l * DFF,
                                               y1_bf, nullptr, nullptr, ML, DFF, D, 16);
        // W2: m97-shape 128x128 BK=32 + split-K=2, 512 blocks; halves: aout(+bias)/tmp
        gemm_w2b<<<512, 256, 0, stream>>>((const unsigned short*)y1_bf,
                                          (const unsigned short*)w2b, bf2 + l * D,
                                          aout, tmp);
        // LN2 (+ fused final head on the last layer)
        add_ln_kernel<<<ML, 64, 0, stream>>>(h_bf, aout, tmp, g2 + l * D, b2 + l * D,
                                             Wf, bff, out, (l == NL - 1) ? 1 : 0);
    }
}

// Round 10
// 539.151 us; speedup vs baseline: 1.0954x; 1.0049x over previous
//
#include <hip/hip_runtime.h>
#include <hip/hip_bf16.h>
#include <math.h>
#include <stdint.h>

#define B 2
#define S 4095
#define LSEQ 4096
#define F_IN 32
#define D 512
#define H 8
#define E 64
#define DFF 2048
#define NL 2
#define U 45
#define EPSL 1e-5f
#define LU (LSEQ * U)
#define HALF_LU (LU / 2)
#define NS 32
#define SLICE 128
#define CASTBLK 3074  // blocks per layer for the cast role ((CAST_N+384+255)/256)

typedef __attribute__((ext_vector_type(8))) short short8;
typedef __attribute__((ext_vector_type(4))) float f32x4;

#define GLD(gp, lp)                                                            \
    __builtin_amdgcn_global_load_lds(                                          \
        (const __attribute__((address_space(1))) void*)(gp),                   \
        (__attribute__((address_space(3))) void*)(lp), 16, 0, 0)

__device__ __forceinline__ unsigned short bf16_bits(float f) {
    __hip_bfloat16 h = __float2bfloat16(f);
    return *(unsigned short*)&h;
}
__device__ __forceinline__ float bits_to_f32(unsigned short s) {
    union { uint32_t u; float f; } c;
    c.u = ((uint32_t)s) << 16;
    return c.f;
}
// monotone sortable key: desc key order == (value desc, index asc) — JAX top_k ties
__device__ __forceinline__ unsigned long long mkey(float v, int index) {
    uint32_t u = __float_as_uint(v);
    uint32_t mono = (u & 0x80000000u) ? ~u : (u | 0x80000000u);
    return ((unsigned long long)mono << 32) | (uint32_t)(0xFFFFFFFFu - (uint32_t)index);
}

// ---------------- Threefry-2x32 (20 rounds), exactly JAX's algorithm ----------------
#define TF_BODY(k0, k1, c0, c1, o0, o1)                                        \
    do {                                                                       \
        uint32_t ks2 = (k0) ^ (k1) ^ 0x1BD11BDAu;                              \
        uint32_t x0 = (c0) + (k0), x1 = (c1) + (k1);                           \
        x0 += x1; x1 = ((x1 << 13) | (x1 >> 19)); x1 ^= x0;                    \
        x0 += x1; x1 = ((x1 << 15) | (x1 >> 17)); x1 ^= x0;                    \
        x0 += x1; x1 = ((x1 << 26) | (x1 >> 6));  x1 ^= x0;                    \
        x0 += x1; x1 = ((x1 << 6) | (x1 >> 26));  x1 ^= x0;                    \
        x0 += (k1); x1 += ks2 + 1u;                                            \
        x0 += x1; x1 = ((x1 << 17) | (x1 >> 15)); x1 ^= x0;                    \
        x0 += x1; x1 = ((x1 << 29) | (x1 >> 3));  x1 ^= x0;                    \
        x0 += x1; x1 = ((x1 << 16) | (x1 >> 16)); x1 ^= x0;                    \
        x0 += x1; x1 = ((x1 << 24) | (x1 >> 8));  x1 ^= x0;                    \
        x0 += ks2; x1 += (k0) + 2u;                                            \
        x0 += x1; x1 = ((x1 << 13) | (x1 >> 19)); x1 ^= x0;                    \
        x0 += x1; x1 = ((x1 << 15) | (x1 >> 17)); x1 ^= x0;                    \
        x0 += x1; x1 = ((x1 << 26) | (x1 >> 6));  x1 ^= x0;                    \
        x0 += x1; x1 = ((x1 << 6) | (x1 >> 26));  x1 ^= x0;                    \
        x0 += (k0); x1 += (k1) + 3u;                                           \
        x0 += x1; x1 = ((x1 << 17) | (x1 >> 15)); x1 ^= x0;                    \
        x0 += x1; x1 = ((x1 << 29) | (x1 >> 3));  x1 ^= x0;                    \
        x0 += x1; x1 = ((x1 << 16) | (x1 >> 16)); x1 ^= x0;                    \
        x0 += x1; x1 = ((x1 << 24) | (x1 >> 8));  x1 ^= x0;                    \
        x0 += (k1); x1 += ks2 + 4u;                                            \
        x0 += x1; x1 = ((x1 << 13) | (x1 >> 19)); x1 ^= x0;                    \
        x0 += x1; x1 = ((x1 << 15) | (x1 >> 17)); x1 ^= x0;                    \
        x0 += x1; x1 = ((x1 << 26) | (x1 >> 6));  x1 ^= x0;                    \
        x0 += x1; x1 = ((x1 << 6) | (x1 >> 26));  x1 ^= x0;                    \
        x0 += ks2; x1 += (k0) + 5u;                                            \
        (o0) = x0; (o1) = x1;                                                  \
    } while (0)

__device__ __forceinline__ void threefry_dev(uint32_t k0, uint32_t k1, uint32_t c0,
                                             uint32_t c1, uint32_t& o0, uint32_t& o1) {
    TF_BODY(k0, k1, c0, c1, o0, o1);
}
static void threefry_host(uint32_t k0, uint32_t k1, uint32_t c0, uint32_t c1,
                          uint32_t& o0, uint32_t& o1) {
    TF_BODY(k0, k1, c0, c1, o0, o1);
}

// ------- FUSED pre-loop: dual-layer weight cast [0,2*CASTBLK) ∥ embed prep ---------
__global__ void prep_cast_kernel(const float* __restrict__ x, const float* __restrict__ We,
                                 __hip_bfloat16* __restrict__ xbf,
                                 __hip_bfloat16* __restrict__ webf,
                                 const float* __restrict__ Wq,
                                 const float* __restrict__ Wk,
                                 const float* __restrict__ Wv,
                                 const float* __restrict__ Wo,
                                 const float* __restrict__ W1,
                                 const float* __restrict__ W2,
                                 const float* __restrict__ bq,
                                 const float* __restrict__ bk,
                                 const float* __restrict__ bv,
                                 __hip_bfloat16* __restrict__ wpool,
                                 float* __restrict__ qkvbias) {
    const int SDD = D * D / 4;       // 65536
    const int SFD = DFF * D / 4;     // 262144
    const int CAST_N = 4 * SDD + 2 * SFD;
    const size_t WPL = (size_t)4 * D * D + 2 * (size_t)DFF * D;
    int bid = blockIdx.x;
    int tid = threadIdx.x;
    if (bid < 2 * CASTBLK) {  // ---- cast role ----
        int l = bid / CASTBLK;
        int u = (bid % CASTBLK) * 256 + tid;
        __hip_bfloat16* base = wpool + (size_t)l * WPL;
        if (u >= CAST_N) {
            int j = u - CAST_N;
            if (j < 384) {
                int seg = (j * 4) >> 9;
                int off = (j * 4) & 511;
                const float* src = (seg == 0) ? bq + l * D
                                 : (seg == 1) ? bk + l * D : bv + l * D;
                *(float4*)(qkvbias + l * 1536 + j * 4) = *(const float4*)(src + off);
            }
            return;
        }
        const float* src;
        __hip_bfloat16* dst;
        int off;
        if (u < SDD)            { src = Wq + (size_t)l * D * D;   dst = base;                       off = u; }
        else if (u < 2 * SDD)   { src = Wk + (size_t)l * D * D;   dst = base + (size_t)D * D;       off = u - SDD; }
        else if (u < 3 * SDD)   { src = Wv + (size_t)l * D * D;   dst = base + (size_t)2 * D * D;   off = u - 2 * SDD; }
        else if (u < 4 * SDD)   { src = Wo + (size_t)l * D * D;   dst = base + (size_t)3 * D * D;   off = u - 3 * SDD; }
        else if (u < 4 * SDD + SFD) { src = W1 + (size_t)l * DFF * D; dst = base + (size_t)4 * D * D; off = u - 4 * SDD; }
        else { src = W2 + (size_t)l * D * DFF; dst = base + (size_t)4 * D * D + (size_t)DFF * D; off = u - 4 * SDD - SFD; }
        float4 v = ((const float4*)src)[off];
        union { unsigned short s[4]; uint2 w; } o;
        o.s[0] = bf16_bits(v.x); o.s[1] = bf16_bits(v.y);
        o.s[2] = bf16_bits(v.z); o.s[3] = bf16_bits(v.w);
        ((uint2*)dst)[off] = o.w;
    } else {  // ---- prep role ----
        int u = (bid - 2 * CASTBLK) * 256 + tid;
        const int NX = B * LSEQ * F_IN / 4;  // 65536
        const int NW = D * F_IN / 4;         // 4096
        if (u < NX) {
            int e0 = u * 4;
            int i = e0 & 31;
            int l = (e0 >> 5) & (LSEQ - 1);
            int b = e0 >> 17;
            union { unsigned short s[4]; uint2 w; } o;
            if (l == 0) {
                o.s[0] = o.s[1] = o.s[2] = o.s[3] = 0;
            } else {
                float4 v = *(const float4*)(x + ((size_t)b * S + (l - 1)) * F_IN + i);
                o.s[0] = bf16_bits(v.x); o.s[1] = bf16_bits(v.y);
                o.s[2] = bf16_bits(v.z); o.s[3] = bf16_bits(v.w);
            }
            ((uint2*)xbf)[u] = o.w;
        } else if (u < NX + NW) {
            int w = u - NX;
            float4 v = ((const float4*)We)[w];
            union { unsigned short s[4]; uint2 w2; } o;
            o.s[0] = bf16_bits(v.x); o.s[1] = bf16_bits(v.y);
            o.s[2] = bf16_bits(v.z); o.s[3] = bf16_bits(v.w);
            ((uint2*)webf)[w] = o.w2;
        }
    }
}

// ------- bf16 MFMA GEMM, BK=32, f32 out (embed) ------------------------------------
__global__ __launch_bounds__(256) void gemm32(const unsigned short* __restrict__ A,
                                              const unsigned short* __restrict__ W,
                                              const float* __restrict__ bias,
                                              float* __restrict__ Cf,
                                              int M, int N, int K) {
    __shared__ unsigned short lds[2 * 128 * 32];
    unsigned short* As = lds;
    unsigned short* Bs = lds + 128 * 32;
    const int tid = threadIdx.x;
    const int m0 = blockIdx.y * 128, n0 = blockIdx.x * 128;
    const int wave = tid >> 6, lane = tid & 63;
    const int wm = (wave >> 1) * 64, wn = (wave & 1) * 64;
    const int quad = lane >> 4, m15 = lane & 15;
    const int srow = tid >> 2, scol = (tid & 3) * 8;
    f32x4 acc[4][4] = {};
    const unsigned short* Ag0 = A + (size_t)(m0 + srow) * K + scol;
    const unsigned short* Ag1 = A + (size_t)(m0 + srow + 64) * K + scol;
    const unsigned short* Wg0 = W + (size_t)(n0 + srow) * K + scol;
    const unsigned short* Wg1 = W + (size_t)(n0 + srow + 64) * K + scol;
    for (int k0 = 0; k0 < K; k0 += 32) {
        __syncthreads();
        GLD(Ag0 + k0, As + tid * 8);
        GLD(Ag1 + k0, As + 2048 + tid * 8);
        GLD(Wg0 + k0, Bs + tid * 8);
        GLD(Wg1 + k0, Bs + 2048 + tid * 8);
        __syncthreads();
        short8 af[4], bfr[4];
#pragma unroll
        for (int mi = 0; mi < 4; ++mi)
            af[mi] = *(const short8*)(As + (wm + mi * 16 + m15) * 32 + quad * 8);
#pragma unroll
        for (int ni = 0; ni < 4; ++ni)
            bfr[ni] = *(const short8*)(Bs + (wn + ni * 16 + m15) * 32 + quad * 8);
#pragma unroll
        for (int mi = 0; mi < 4; ++mi)
#pragma unroll
            for (int ni = 0; ni < 4; ++ni)
                acc[mi][ni] = __builtin_amdgcn_mfma_f32_16x16x32_bf16(
                    af[mi], bfr[ni], acc[mi][ni], 0, 0, 0);
    }
#pragma unroll
    for (int mi = 0; mi < 4; ++mi) {
        int mg = m0 + wm + mi * 16 + quad * 4;
#pragma unroll
        for (int ni = 0; ni < 4; ++ni) {
            int ng = n0 + wn + ni * 16 + m15;
            float bv = bias[ng];
#pragma unroll
            for (int r = 0; r < 4; ++r)
                Cf[(size_t)(mg + r) * N + ng] = acc[mi][ni][r] + bv;
        }
    }
}

// ------- posenc: h_bf = bf16((l==0 ? cls : emb) + PE) ------------------------------
__global__ void posenc_kernel(const float* __restrict__ emb, const float* __restrict__ cls,
                              __hip_bfloat16* __restrict__ hbf) {
    int gid = blockIdx.x * blockDim.x + threadIdx.x;
    if (gid >= B * LSEQ * D) return;
    int d = gid % D;
    int l = (gid / D) % LSEQ;
    float v = (l == 0) ? cls[d] : emb[gid];
    int i = d >> 1;
    float divv = expf((float)(2 * i) * (float)(-9.210340371976184 / 512.0));
    float ang = (float)l * divv;
    v += (d & 1) ? cosf(ang) : sinf(ang);
    hbf[gid] = __float2bfloat16(v);
}

// ------- DEEP-PIPELINED bf16 MFMA GEMM: 128x128, BK=32, TRIPLE-buffer, raw barriers
// Counted vmcnt keeps 2 K-tiles (8 global_load_lds) in flight ACROSS the barrier:
// per-wave vmcnt(8) retires each wave's OWN tile-i loads (its oldest); the raw
// s_barrier joins all waves, so tile i is fully landed without draining the
// prefetches (old __syncthreads forced vmcnt(0) -> ~700cy serial stall per iter,
// measured ~420 TF at these K=512..2048 shapes).
// Race audit: stage writes buf (i+2)%3 != consuming buf i%3; second barrier after
// lgkmcnt(0)-retired frag reads protects buf i%3 before iter i+1 stages into it.
// sched_barrier(0) after each wait pins codegen (guide rule #18).
template <int MODE>
__global__ __launch_bounds__(256) void gemm_pipe(const unsigned short* __restrict__ A,
                                                 const unsigned short* __restrict__ W,
                                                 const float* __restrict__ bias,
                                                 void* __restrict__ C0,
                                                 void* __restrict__ C1,
                                                 void* __restrict__ C2,
                                                 int M, int N, int K, int NBN) {
    __shared__ unsigned short As[3][128 * 32];
    __shared__ unsigned short Bs[3][128 * 32];
    const int tid = threadIdx.x;
    const int NBM = M >> 7;
    const int bid = blockIdx.x;
    const int xcd = bid & 7, local = bid >> 3;
    const int m_t = xcd * (NBM >> 3) + local / NBN;
    const int n_t = local % NBN;
    const int m0 = m_t * 128, n0 = n_t * 128;
    const int wave = tid >> 6, lane = tid & 63;
    const int wm = (wave >> 1) * 64, wn = (wave & 1) * 64;
    const int quad = lane >> 4, m15 = lane & 15;
    const int srow = tid >> 2, scol = (tid & 3) * 8;
    f32x4 acc[4][4] = {};
    const unsigned short* Ag0 = A + (size_t)(m0 + srow) * K + scol;
    const unsigned short* Ag1 = A + (size_t)(m0 + srow + 64) * K + scol;
    const unsigned short* Wg0 = W + (size_t)(n0 + srow) * K + scol;
    const unsigned short* Wg1 = W + (size_t)(n0 + srow + 64) * K + scol;
#define STAGE_P(buf, k0)                                                       \
    do {                                                                       \
        GLD(Ag0 + (k0), As[buf] + tid * 8);                                    \
        GLD(Ag1 + (k0), As[buf] + 2048 + tid * 8);                             \
        GLD(Wg0 + (k0), Bs[buf] + tid * 8);                                    \
        GLD(Wg1 + (k0), Bs[buf] + 2048 + tid * 8);                             \
    } while (0)
    const int NIT = K >> 5;
    STAGE_P(0, 0);
    STAGE_P(1, 32);
    for (int i = 0; i < NIT; ++i) {
        int cur = i % 3;
        if (i + 2 < NIT) STAGE_P((i + 2) % 3, (i + 2) * 32);
        int rem = NIT - 1 - i;
        if (rem >= 2)      asm volatile("s_waitcnt vmcnt(8)" ::: "memory");
        else if (rem == 1) asm volatile("s_waitcnt vmcnt(4)" ::: "memory");
        else               asm volatile("s_waitcnt vmcnt(0)" ::: "memory");
        __builtin_amdgcn_sched_barrier(0);
        __builtin_amdgcn_s_barrier();   // tile i fully landed for all waves
        __builtin_amdgcn_sched_barrier(0);
        short8 af[4], bfr[4];
#pragma unroll
        for (int mi = 0; mi < 4; ++mi)
            af[mi] = *(const short8*)(As[cur] + (wm + mi * 16 + m15) * 32 + quad * 8);
#pragma unroll
        for (int ni = 0; ni < 4; ++ni)
            bfr[ni] = *(const short8*)(Bs[cur] + (wn + ni * 16 + m15) * 32 + quad * 8);
        asm volatile("s_waitcnt lgkmcnt(0)" ::: "memory");
        __builtin_amdgcn_sched_barrier(0);
        __builtin_amdgcn_s_barrier();   // all waves' reads of buf cur done
        __builtin_amdgcn_sched_barrier(0);
#pragma unroll
        for (int mi = 0; mi < 4; ++mi)
#pragma unroll
            for (int ni = 0; ni < 4; ++ni)
                acc[mi][ni] = __builtin_amdgcn_mfma_f32_16x16x32_bf16(
                    af[mi], bfr[ni], acc[mi][ni], 0, 0, 0);
    }
#undef STAGE_P
#pragma unroll
    for (int mi = 0; mi < 4; ++mi) {
        int mg = m0 + wm + mi * 16 + quad * 4;
#pragma unroll
        for (int ni = 0; ni < 4; ++ni) {
            int ng = n0 + wn + ni * 16 + m15;
            float bv = bias[ng];
#pragma unroll
            for (int r = 0; r < 4; ++r) {
                float v = acc[mi][ni][r] + bv;
                if (MODE == 1) {
                    ((__hip_bfloat16*)C0)[(size_t)(mg + r) * N + ng] = __float2bfloat16(v);
                } else if (MODE == 2) {
                    ((__hip_bfloat16*)C0)[(size_t)(mg + r) * N + ng] =
                        __float2bfloat16(fmaxf(v, 0.f));
                } else {  // QKV: N=1536, segments of 512, all bf16
                    int seg = ng >> 9;
                    int col = ng & 511;
                    __hip_bfloat16* dst = (seg == 0) ? (__hip_bfloat16*)C0
                                        : (seg == 1) ? (__hip_bfloat16*)C1
                                                     : (__hip_bfloat16*)C2;
                    dst[(size_t)(mg + r) * D + col] = __float2bfloat16(v);
                }
            }
        }
    }
}

// ------- W2 GEMM: m97-shape 128x128 BK=32 pipelined + split-K=2, f32 out -----------
// (kept on the old 2-phase schedule as the control for this round's pipeline change)
__global__ __launch_bounds__(256) void gemm_w2b(const unsigned short* __restrict__ A,
                                                const unsigned short* __restrict__ W,
                                                const float* __restrict__ bias,
                                                float* __restrict__ C0,
                                                float* __restrict__ C1) {
    const int K = 2048, N = 512, KH = 1024;
    __shared__ unsigned short As[2][128 * 32];
    __shared__ unsigned short Bs[2][128 * 32];
    const int tid = threadIdx.x;
    const int bid = blockIdx.x;
    const int xcd = bid & 7, local = bid >> 3;
    const int m_t = xcd * 8 + (local >> 3);
    const int n_t = (local >> 1) & 3;
    const int ks = local & 1;
    const int m0 = m_t * 128, n0 = n_t * 128, kb = ks * KH;
    const int wave = tid >> 6, lane = tid & 63;
    const int wm = (wave >> 1) * 64, wn = (wave & 1) * 64;
    const int quad = lane >> 4, m15 = lane & 15;
    const int srow = tid >> 2, scol = (tid & 3) * 8;
    f32x4 acc[4][4] = {};
    const unsigned short* Ag0 = A + (size_t)(m0 + srow) * K + kb + scol;
    const unsigned short* Ag1 = A + (size_t)(m0 + srow + 64) * K + kb + scol;
    const unsigned short* Wg0 = W + (size_t)(n0 + srow) * K + kb + scol;
    const unsigned short* Wg1 = W + (size_t)(n0 + srow + 64) * K + kb + scol;
    GLD(Ag0, As[0] + tid * 8);
    GLD(Ag1, As[0] + 2048 + tid * 8);
    GLD(Wg0, Bs[0] + tid * 8);
    GLD(Wg1, Bs[0] + 2048 + tid * 8);
    int cur = 0;
    for (int k0 = 0; k0 < KH; k0 += 32) {
        __syncthreads();
        int kn = k0 + 32;
        if (kn < KH) {
            GLD(Ag0 + kn, As[cur ^ 1] + tid * 8);
            GLD(Ag1 + kn, As[cur ^ 1] + 2048 + tid * 8);
            GLD(Wg0 + kn, Bs[cur ^ 1] + tid * 8);
            GLD(Wg1 + kn, Bs[cur ^ 1] + 2048 + tid * 8);
        }
        short8 af[4], bfr[4];
#pragma unroll
        for (int mi = 0; mi < 4; ++mi)
            af[mi] = *(const short8*)(As[cur] + (wm + mi * 16 + m15) * 32 + quad * 8);
#pragma unroll
        for (int ni = 0; ni < 4; ++ni)
            bfr[ni] = *(const short8*)(Bs[cur] + (wn + ni * 16 + m15) * 32 + quad * 8);
#pragma unroll
        for (int mi = 0; mi < 4; ++mi)
#pragma unroll
            for (int ni = 0; ni < 4; ++ni)
                acc[mi][ni] = __builtin_amdgcn_mfma_f32_16x16x32_bf16(
                    af[mi], bfr[ni], acc[mi][ni], 0, 0, 0);
        cur ^= 1;
    }
    float* Cf = ks ? C1 : C0;
#pragma unroll
    for (int mi = 0; mi < 4; ++mi) {
        int mg = m0 + wm + mi * 16 + quad * 4;
#pragma unroll
        for (int ni = 0; ni < 4; ++ni) {
            int ng = n0 + wn + ni * 16 + m15;
            float bv = ks ? 0.f : bias[ng];
#pragma unroll
            for (int r = 0; r < 4; ++r)
                Cf[(size_t)(mg + r) * N + ng] = acc[mi][ni][r] + bv;
        }
    }
}

// -------- M-score [0,8192) ∥ acorr bulk clear [8192,8320) --------------------------
__global__ __launch_bounds__(256) void mscore_kernel(const __hip_bfloat16* __restrict__ qbf,
                                                     const __hip_bfloat16* __restrict__ kbf,
                                                     uint32_t k2a, uint32_t k2b,
                                                     float* __restrict__ Mv,
                                                     float* __restrict__ acorr) {
    __shared__ float Sbuf[U][8];
    __shared__ int sidx[U];
    int bid = blockIdx.x;
    int tid = threadIdx.x;
    if (bid >= B * LSEQ) {  // ---- acorr clear role ----
        int vb = bid - B * LSEQ;  // 0..127
        float4 z = {0.f, 0.f, 0.f, 0.f};
        float4* p = (float4*)acorr;
#pragma unroll
        for (int i = 0; i < 32; ++i)
            p[(size_t)i * 32768 + vb * 256 + tid] = z;
        return;
    }
    int b = bid & 1;
    int l = bid >> 1;
    int wave = tid >> 6, lane = tid & 63;
    if (tid < U) {
        int i = l * U + tid;
        uint32_t c0 = (i < HALF_LU) ? (uint32_t)i : (uint32_t)(i - HALF_LU);
        uint32_t o0, o1;
        threefry_dev(k2a, k2b, c0, c0 + HALF_LU, o0, o1);
        sidx[tid] = (int)(((i < HALF_LU) ? o0 : o1) & 4095u);
    }
    const unsigned short* qr =
        (const unsigned short*)qbf + ((size_t)(b * LSEQ) + l) * D + lane * 8;
    union { uint4 u; unsigned short s[8]; } qv;
    qv.u = *(const uint4*)qr;
    float qa[8];
#pragma unroll
    for (int j = 0; j < 8; ++j) qa[j] = bits_to_f32(qv.s[j]);
    __syncthreads();
    const unsigned short* kbase = (const unsigned short*)(kbf + (size_t)(b * LSEQ) * D);
    for (int t = wave; t < U; t += 12) {
        int tb = t + 4, tc = t + 8;
        bool hb = tb < U, hc = tc < U;
        union { uint4 u; unsigned short s[8]; } kva, kvb, kvc;
        kva.u = *(const uint4*)(kbase + (size_t)sidx[t] * D + lane * 8);
        if (hb) kvb.u = *(const uint4*)(kbase + (size_t)sidx[tb] * D + lane * 8);
        if (hc) kvc.u = *(const uint4*)(kbase + (size_t)sidx[tc] * D + lane * 8);
        {
            float p = 0.f;
#pragma unroll
            for (int j = 0; j < 8; ++j) p += qa[j] * bits_to_f32(kva.s[j]);
            p += __shfl_xor(p, 1);
            p += __shfl_xor(p, 2);
            p += __shfl_xor(p, 4);
            if ((lane & 7) == 0) Sbuf[t][lane >> 3] = p;
        }
        if (hb) {
            float p = 0.f;
#pragma unroll
            for (int j = 0; j < 8; ++j) p += qa[j] * bits_to_f32(kvb.s[j]);
            p += __shfl_xor(p, 1);
            p += __shfl_xor(p, 2);
            p += __shfl_xor(p, 4);
            if ((lane & 7) == 0) Sbuf[tb][lane >> 3] = p;
        }
        if (hc) {
            float p = 0.f;
#pragma unroll
            for (int j = 0; j < 8; ++j) p += qa[j] * bits_to_f32(kvc.s[j]);
            p += __shfl_xor(p, 1);
            p += __shfl_xor(p, 2);
            p += __shfl_xor(p, 4);
            if ((lane & 7) == 0) Sbuf[tc][lane >> 3] = p;
        }
    }
    __syncthreads();
    if (tid < 8) {
        float mx = -INFINITY, sm = 0.f;
        for (int t = 0; t < U; ++t) {
            float v = Sbuf[t][tid];
            mx = fmaxf(mx, v);
            sm += v;
        }
        Mv[((size_t)b * H + tid) * LSEQ + l] = mx - sm / (float)LSEQ;
    }
}

// ------- top-k phase A: bitonic sort each 256-chunk desc, emit top-45 keys ---------
__global__ __launch_bounds__(256) void topk_chunk_kernel(const float* __restrict__ Mv,
                                                         unsigned long long* __restrict__ cand) {
    __shared__ unsigned long long sk[256];
    int blk = blockIdx.x;  // B*H*16
    int chunk = blk & 15, bh = blk >> 4;
    int tid = threadIdx.x;
    int gi = chunk * 256 + tid;
    sk[tid] = mkey(Mv[(size_t)bh * LSEQ + gi], gi);
    __syncthreads();
    for (int k = 2; k <= 256; k <<= 1) {
        for (int j = k >> 1; j > 0; j >>= 1) {
            int ixj = tid ^ j;
            if (ixj > tid) {
                unsigned long long a = sk[tid], b = sk[ixj];
                bool desc = ((tid & k) == 0);
                if (desc ? (a < b) : (a > b)) { sk[tid] = b; sk[ixj] = a; }
            }
            __syncthreads();
        }
    }
    if (tid < U) cand[((size_t)bh * 16 + chunk) * U + tid] = sk[tid];
}

// ------- FUSED: top-k merge [0,16) ∥ vmean partial [16,144) ∥ flag clear [144,152) -
__global__ __launch_bounds__(256) void topkmerge_vmean_kernel(
        const unsigned long long* __restrict__ cand, int* __restrict__ top,
        const __hip_bfloat16* __restrict__ v, float* __restrict__ part,
        unsigned char* __restrict__ flags) {
    __shared__ unsigned long long sk[1024];
    __shared__ float red[4][64];
    int blk = blockIdx.x;
    int tid = threadIdx.x;
    if (blk < B * H) {  // ---- topk_merge role ----
        int bh = blk;
        for (int e = tid; e < 1024; e += 256)
            sk[e] = (e < 16 * U) ? cand[(size_t)bh * 16 * U + e] : 0ull;
        __syncthreads();
        for (int k = 2; k <= 1024; k <<= 1) {
            for (int j = k >> 1; j > 0; j >>= 1) {
                for (int e = tid; e < 1024; e += 256) {
                    int ixj = e ^ j;
                    if (ixj > e) {
                        unsigned long long a = sk[e], b = sk[ixj];
                        bool desc = ((e & k) == 0);
                        if (desc ? (a < b) : (a > b)) { sk[e] = b; sk[ixj] = a; }
                    }
                }
                __syncthreads();
            }
        }
        if (tid < U)
            top[bh * U + tid] = (int)(0xFFFFFFFFu - (uint32_t)(sk[tid] & 0xFFFFFFFFu));
    } else if (blk < B * H + B * H * 8) {  // ---- vmean_part role ----
        int vb = blk - B * H;  // 0..127
        int seg = vb & 7, hh = (vb >> 3) & 7, b = vb >> 6;
        int e = tid & 63, rg = tid >> 6;
        const __hip_bfloat16* vp =
            v + ((size_t)(b * LSEQ) + seg * 512) * D + hh * 64 + e;
        float acc = 0.f;
        for (int r = rg; r < 512; r += 4) acc += __bfloat162float(vp[(size_t)r * D]);
        red[rg][e] = acc;
        __syncthreads();
        if (tid < 64)
            part[(size_t)vb * 64 + tid] =
                red[0][tid] + red[1][tid] + red[2][tid] + red[3][tid];
    } else {  // ---- flag clear role: 8 blocks x 256 x 4B = 8192 B ----
        int fb = blk - (B * H + B * H * 8);
        ((int*)flags)[fb * 256 + tid] = 0;
    }
}

// ------- FUSED: attnred corr scatter [0,720) ∥ wo_base [720,976) -------------------
__global__ __launch_bounds__(256) void attnred_wobase_kernel(
        const float* __restrict__ Opart, const float* __restrict__ msum,
        const float* __restrict__ vpart, const unsigned short* __restrict__ wob,
        const int* __restrict__ top, float* __restrict__ acorr,
        unsigned char* __restrict__ flags, const float* __restrict__ bo,
        float* __restrict__ base) {
    __shared__ float dlt[E];
    int bid = blockIdx.x;
    int tid = threadIdx.x;
    if (bid < B * H * U) {  // ---- attnred + scatter role ----
        int t = bid % U;
        int bh = bid / U;
        int b = bh >> 3, hh = bh & 7;
        if (tid < 64) {
            int lane = tid;
            float m_s = -INFINITY, ss = 0.f;
            if (lane < NS) {
                size_t base2 = (((size_t)bh * NS + lane) * U + t) * 2;
                m_s = msum[base2];
                ss = msum[base2 + 1];
            }
            float M = m_s;
            for (int off = 32; off; off >>= 1) M = fmaxf(M, __shfl_xor(M, off));
            float e_s = (lane < NS) ? __expf(m_s - M) : 0.f;
            float d = ss * e_s;
            for (int off = 32; off; off >>= 1) d += __shfl_xor(d, off);
            float acc = 0.f;
            for (int s = 0; s < NS; ++s) {
                float w = __shfl(e_s, s);
                acc += w * Opart[(((size_t)bh * NS + s) * U + t) * 64 + lane];
            }
            float vmv = 0.f;
#pragma unroll
            for (int s = 0; s < 8; ++s) vmv += vpart[((size_t)bh * 8 + s) * 64 + lane];
            dlt[lane] = acc / d - vmv / (float)LSEQ;
        }
        __syncthreads();
        int r = top[bh * U + t];
        if (tid == 0) flags[b * LSEQ + r] = 1;
        float* arow = acorr + (size_t)(b * LSEQ + r) * D;
        for (int n = tid; n < D; n += 256) {
            const unsigned short* wr = wob + (size_t)n * D + hh * E;
            float acc = 0.f;
#pragma unroll
            for (int v4 = 0; v4 < 8; ++v4) {
                union { uint4 u; unsigned short s[8]; } w;
                w.u = *(const uint4*)(wr + v4 * 8);
#pragma unroll
                for (int j = 0; j < 8; ++j)
                    acc += dlt[v4 * 8 + j] * bits_to_f32(w.s[j]);
            }
            atomicAdd(arow + n, acc);
        }
    } else {  // ---- wo_base role ----
        int wb = bid - B * H * U;           // 0..255
        int b = wb >> 7;
        int n = (wb & 127) * 4 + (tid >> 6);
        int lane = tid & 63;
        float vmv[8];
#pragma unroll
        for (int j = 0; j < 8; ++j) {
            int idx = lane * 8 + j;
            int hh = idx >> 6, e = idx & 63;
            float acc = 0.f;
#pragma unroll
            for (int s = 0; s < 8; ++s)
                acc += vpart[((size_t)(b * 8 + hh) * 8 + s) * 64 + e];
            vmv[j] = acc / (float)LSEQ;
        }
        union { uint4 u; unsigned short s[8]; } w;
        w.u = *(const uint4*)(wob + (size_t)n * D + lane * 8);
        float p = vmv[0] * bits_to_f32(w.s[0]) + vmv[1] * bits_to_f32(w.s[1]) +
                  vmv[2] * bits_to_f32(w.s[2]) + vmv[3] * bits_to_f32(w.s[3]) +
                  vmv[4] * bits_to_f32(w.s[4]) + vmv[5] * bits_to_f32(w.s[5]) +
                  vmv[6] * bits_to_f32(w.s[6]) + vmv[7] * bits_to_f32(w.s[7]);
        for (int off = 32; off; off >>= 1) p += __shfl_xor(p, off);
        if (lane == 0) base[(size_t)b * D + n] = p + bo[n];
    }
}

// -------- flash-style MFMA attention partial: block = (slice, h, b) ----------------
__global__ __launch_bounds__(256) void attn_part(const __hip_bfloat16* __restrict__ qbf,
                                                 const __hip_bfloat16* __restrict__ kbf,
                                                 const __hip_bfloat16* __restrict__ vbf,
                                                 const int* __restrict__ top,
                                                 float* __restrict__ Opart,
                                                 float* __restrict__ msum) {
    __shared__ unsigned short Qs[48 * 72];
    __shared__ unsigned short Ks[SLICE * 72];
    __shared__ unsigned short Vs[SLICE * 68];
    __shared__ unsigned short Ps[48 * 136];
    __shared__ float mred[48][4];
    __shared__ float sred[48][4];
    const int slice = blockIdx.x, hh = blockIdx.y, b = blockIdx.z;
    const int bh = b * H + hh;
    const int tid = threadIdx.x;
    const int s0 = slice * SLICE;
    for (int i = tid; i < 48 * 64; i += 256) {
        int t = i >> 6, e = i & 63;
        unsigned short v = 0;
        if (t < U) {
            int r = top[bh * U + t];
            v = ((const unsigned short*)qbf)[((size_t)(b * LSEQ) + r) * D + hh * E + e];
        }
        Qs[t * 72 + e] = v;
    }
    {
        const uint4* src = (const uint4*)(kbf + ((size_t)(b * LSEQ) + s0) * D + hh * E);
        for (int i = tid; i < SLICE * 8; i += 256) {
            int r = i >> 3, c = i & 7;
            uint4 d = src[(size_t)r * 64 + c];
            *(uint4*)(Ks + r * 72 + c * 8) = d;
        }
    }
    {
        const uint2* src = (const uint2*)(vbf + ((size_t)(b * LSEQ) + s0) * D + hh * E);
        for (int i = tid; i < SLICE * 16; i += 256) {
            int r = i >> 4, c = i & 15;
            uint2 d = src[(size_t)r * 128 + c];
            *(uint2*)(Vs + r * 68 + c * 4) = d;
        }
    }
    __syncthreads();
    const int wave = tid >> 6, lane = tid & 63;
    const int quad = lane >> 4, m15 = lane & 15;
    const int wc = wave * 32;
    f32x4 acc[3][2] = {};
#pragma unroll
    for (int ks = 0; ks < 2; ++ks) {
        short8 af[3], bfr[2];
#pragma unroll
        for (int mt = 0; mt < 3; ++mt)
            af[mt] = *(const short8*)(Qs + (mt * 16 + m15) * 72 + ks * 32 + quad * 8);
#pragma unroll
        for (int nt = 0; nt < 2; ++nt)
            bfr[nt] = *(const short8*)(Ks + (wc + nt * 16 + m15) * 72 + ks * 32 + quad * 8);
#pragma unroll
        for (int mt = 0; mt < 3; ++mt)
#pragma unroll
            for (int nt = 0; nt < 2; ++nt)
                acc[mt][nt] = __builtin_amdgcn_mfma_f32_16x16x32_bf16(
                    af[mt], bfr[nt], acc[mt][nt], 0, 0, 0);
    }
    float sc[3][2][4];
#pragma unroll
    for (int mt = 0; mt < 3; ++mt)
#pragma unroll
        for (int nt = 0; nt < 2; ++nt)
#pragma unroll
            for (int r = 0; r < 4; ++r) sc[mt][nt][r] = acc[mt][nt][r] * 0.125f;
#pragma unroll
    for (int mt = 0; mt < 3; ++mt)
#pragma unroll
        for (int r = 0; r < 4; ++r) {
            float mv = fmaxf(sc[mt][0][r], sc[mt][1][r]);
            mv = fmaxf(mv, __shfl_xor(mv, 1));
            mv = fmaxf(mv, __shfl_xor(mv, 2));
            mv = fmaxf(mv, __shfl_xor(mv, 4));
            mv = fmaxf(mv, __shfl_xor(mv, 8));
            if (m15 == 0) mred[mt * 16 + quad * 4 + r][wave] = mv;
        }
    __syncthreads();
#pragma unroll
    for (int mt = 0; mt < 3; ++mt)
#pragma unroll
        for (int r = 0; r < 4; ++r) {
            int row = mt * 16 + quad * 4 + r;
            float ms = fmaxf(fmaxf(mred[row][0], mred[row][1]),
                             fmaxf(mred[row][2], mred[row][3]));
            float p0 = __expf(sc[mt][0][r] - ms);
            float p1 = __expf(sc[mt][1][r] - ms);
            float sv = p0 + p1;
            sv += __shfl_xor(sv, 1);
            sv += __shfl_xor(sv, 2);
            sv += __shfl_xor(sv, 4);
            sv += __shfl_xor(sv, 8);
            if (m15 == 0) sred[row][wave] = sv;
            Ps[row * 136 + wc + m15] = bf16_bits(p0);
            Ps[row * 136 + wc + 16 + m15] = bf16_bits(p1);
        }
    __syncthreads();
    if (tid < U) {
        float mm = fmaxf(fmaxf(mred[tid][0], mred[tid][1]),
                         fmaxf(mred[tid][2], mred[tid][3]));
        float ss = sred[tid][0] + sred[tid][1] + sred[tid][2] + sred[tid][3];
        size_t base = (((size_t)bh * NS + slice) * U + tid) * 2;
        msum[base] = mm;
        msum[base + 1] = ss;
    }
    f32x4 apv[3] = {};
#pragma unroll
    for (int ks = 0; ks < 4; ++ks) {
        short8 bv;
#pragma unroll
        for (int j = 0; j < 8; ++j)
            bv[j] = (short)Vs[(ks * 32 + quad * 8 + j) * 68 + wave * 16 + m15];
        short8 af2[3];
#pragma unroll
        for (int mt = 0; mt < 3; ++mt)
            af2[mt] = *(const short8*)(Ps + (mt * 16 + m15) * 136 + ks * 32 + quad * 8);
#pragma unroll
        for (int mt = 0; mt < 3; ++mt)
            apv[mt] = __builtin_amdgcn_mfma_f32_16x16x32_bf16(af2[mt], bv, apv[mt], 0, 0, 0);
    }
    size_t obase = ((size_t)bh * NS + slice) * U;
#pragma unroll
    for (int mt = 0; mt < 3; ++mt)
#pragma unroll
        for (int r = 0; r < 4; ++r) {
            int row = mt * 16 + quad * 4 + r;
            if (row < U)
                Opart[(obase + row) * 64 + wave * 16 + m15] = apv[mt][r];
        }
}

// -------- LN1: hbf = LayerNorm(hbf + base[b] + sparse corr) * g + b (bf16 stream) --
__global__ __launch_bounds__(64) void add_ln_base_kernel(__hip_bfloat16* __restrict__ hbf,
                                                         const float* __restrict__ base,
                                                         const float* __restrict__ acorr,
                                                         const unsigned char* __restrict__ flags,
                                                         const float* __restrict__ g,
                                                         const float* __restrict__ bb) {
    int row = blockIdx.x;
    int b = row >> 12;
    int lane = threadIdx.x;
    unsigned short* hp = (unsigned short*)hbf + (size_t)row * D;
    const float* bp = base + (size_t)b * D;
    const float* ap = acorr + (size_t)row * D;
    bool has = flags[row] != 0;
    float x[8];
    float sum = 0.f;
#pragma unroll
    for (int j = 0; j < 8; ++j) {
        float a = bp[lane + 64 * j];
        if (has) a += ap[lane + 64 * j];
        x[j] = bits_to_f32(hp[lane + 64 * j]) + a;
        sum += x[j];
    }
    for (int off = 32; off; off >>= 1) sum += __shfl_xor(sum, off);
    float mu = sum / (float)D;
    float vs = 0.f;
#pragma unroll
    for (int j = 0; j < 8; ++j) {
        float dd = x[j] - mu;
        vs += dd * dd;
    }
    for (int off = 32; off; off >>= 1) vs += __shfl_xor(vs, off);
    float inv = 1.f / sqrtf(vs / (float)D + EPSL);
#pragma unroll
    for (int j = 0; j < 8; ++j) {
        float o = (x[j] - mu) * inv * g[lane + 64 * j] + bb[lane + 64 * j];
        hp[lane + 64 * j] = bf16_bits(o);
    }
}

// -------- LN2: hbf = LayerNorm(hbf + a + a2) * g + b; last layer fuses final head --
__global__ __launch_bounds__(64) void add_ln_kernel(__hip_bfloat16* __restrict__ hbf,
                                                    const float* __restrict__ a,
                                                    const float* __restrict__ a2,
                                                    const float* __restrict__ g,
                                                    const float* __restrict__ bb,
                                                    const float* __restrict__ Wf,
                                                    const float* __restrict__ bf,
                                                    float* __restrict__ out,
                                                    int fuseFinal) {
    int row = blockIdx.x;
    int lane = threadIdx.x;
    unsigned short* hp = (unsigned short*)hbf + (size_t)row * D;
    const float* ap = a + (size_t)row * D;
    const float* ap2 = a2 + (size_t)row * D;
    float x[8];
    float sum = 0.f;
#pragma unroll
    for (int j = 0; j < 8; ++j) {
        x[j] = bits_to_f32(hp[lane + 64 * j]) + ap[lane + 64 * j] + ap2[lane + 64 * j];
        sum += x[j];
    }
    for (int off = 32; off; off >>= 1) sum += __shfl_xor(sum, off);
    float mu = sum / (float)D;
    float vs = 0.f;
#pragma unroll
    for (int j = 0; j < 8; ++j) {
        float dd = x[j] - mu;
        vs += dd * dd;
    }
    for (int off = 32; off; off >>= 1) vs += __shfl_xor(vs, off);
    float inv = 1.f / sqrtf(vs / (float)D + EPSL);
    bool doFinal = fuseFinal && ((row & (LSEQ - 1)) == 0);
    float facc = 0.f;
#pragma unroll
    for (int j = 0; j < 8; ++j) {
        float o = (x[j] - mu) * inv * g[lane + 64 * j] + bb[lane + 64 * j];
        unsigned short ob = bf16_bits(o);
        hp[lane + 64 * j] = ob;
        if (doFinal) facc += bits_to_f32(ob) * Wf[lane + 64 * j];
    }
    if (doFinal) {
        for (int off = 32; off; off >>= 1) facc += __shfl_xor(facc, off);
        if (lane == 0) out[row >> 12] = facc + bf[0];
    }
}

extern "C" void kernel_launch(void* const* d_in, const int* in_sizes, int n_in,
                              void* d_out, int out_size, void* d_ws, size_t ws_size,
                              hipStream_t stream) {
    (void)in_sizes; (void)n_in; (void)out_size; (void)ws_size;
    const float* x   = (const float*)d_in[0];
    const float* We  = (const float*)d_in[1];
    const float* be  = (const float*)d_in[2];
    const float* cls = (const float*)d_in[3];
    const float* Wq  = (const float*)d_in[4];
    const float* bq  = (const float*)d_in[5];
    const float* Wk  = (const float*)d_in[6];
    const float* bk  = (const float*)d_in[7];
    const float* Wv  = (const float*)d_in[8];
    const float* bv  = (const float*)d_in[9];
    const float* Wo  = (const float*)d_in[10];
    const float* bo  = (const float*)d_in[11];
    const float* g1  = (const float*)d_in[12];
    const float* b1  = (const float*)d_in[13];
    const float* g2  = (const float*)d_in[14];
    const float* b2  = (const float*)d_in[15];
    const float* W1  = (const float*)d_in[16];
    const float* bf1 = (const float*)d_in[17];
    const float* W2  = (const float*)d_in[18];
    const float* bf2 = (const float*)d_in[19];
    const float* Wf  = (const float*)d_in[20];
    const float* bff = (const float*)d_in[21];
    float* out = (float*)d_out;

    float* ws = (float*)d_ws;
    const size_t NT = (size_t)B * LSEQ * D;  // 4,194,304
    float* aout = ws + NT;                    // [NT, 2NT): W2 ks0 output (kbf overlay)
    __hip_bfloat16* kbf    = (__hip_bfloat16*)(ws + NT);      // overlays aout
    __hip_bfloat16* q_bf   = (__hip_bfloat16*)(ws + 2 * NT);  // NT bf16
    __hip_bfloat16* y1_bf  = (__hip_bfloat16*)(ws + 2 * NT);  // overlays q post-attn
    __hip_bfloat16* v_bf   = (__hip_bfloat16*)(ws + 4 * NT);
    __hip_bfloat16* h_bf   = (__hip_bfloat16*)(ws + 5 * NT);
    float* emb   = ws;   // [0, NT): pre-loop only
    float* acorr = ws;   // [0, NT): in-loop sparse attn corrections (no kbf overlay!)
    float* tmp   = ws;   // [0, NT): W2 split-K partial (after add_ln_base consumed acorr)
    float* Opart = ws + 3 * NT;
    float* msumb = Opart + (size_t)B * H * NS * U * 64;
    float* wpool = ws + 5 * NT + NT / 2;
    const size_t WPL = (size_t)4 * D * D + 2 * (size_t)DFF * D;  // bf16 elems/layer
    __hip_bfloat16* wpool_bf = (__hip_bfloat16*)wpool;           // 2 layers contiguous
    float* after_w = wpool + (2 * WPL) / 2;
    float* Mbuf = after_w;
    int* top    = (int*)(Mbuf + (size_t)B * H * LSEQ);
    float* vpart  = (float*)(top + B * H * U);
    float* baseb  = vpart + (size_t)128 * 64;
    __hip_bfloat16* xbf  = (__hip_bfloat16*)(baseb + (size_t)B * D);   // B*LSEQ*F_IN
    __hip_bfloat16* webf = xbf + (size_t)B * LSEQ * F_IN;              // D*F_IN
    unsigned long long* cand =
        (unsigned long long*)(((uintptr_t)(webf + (size_t)D * F_IN) + 7) & ~(uintptr_t)7);
    float* qkvbias = (float*)(cand + (size_t)B * H * 16 * U);          // 2 x 1536 floats
    unsigned char* flags = (unsigned char*)(qkvbias + 2 * 1536);       // B*LSEQ bytes

    const int ML = B * LSEQ;  // 8192
    dim3 gD(D / 128, ML / 128);
    const int NPREP = (B * LSEQ * F_IN / 4 + D * F_IN / 4 + 255) / 256;  // 272

    // ---- pre-loop: merged (dual-layer cast ∥ embed prep); embed GEMM + posenc ----
    prep_cast_kernel<<<2 * CASTBLK + NPREP, 256, 0, stream>>>(
        x, We, xbf, webf, Wq, Wk, Wv, Wo, W1, W2, bq, bk, bv, wpool_bf, qkvbias);
    gemm32<<<gD, 256, 0, stream>>>((const unsigned short*)xbf,
                                   (const unsigned short*)webf, be, emb, ML, D, F_IN);
    posenc_kernel<<<(B * LSEQ * D + 255) / 256, 256, 0, stream>>>(emb, cls, h_bf);

    for (int l = 0; l < NL; ++l) {
        // host-side threefry key schedule for this layer's sample indices
        uint32_t f0, f1, a0, a1, bb0, bb1;
        threefry_host(0u, 42u, 0u, (uint32_t)l, f0, f1);
        threefry_host(f0, f1, 0u, 2u, a0, a1);
        threefry_host(f0, f1, 1u, 3u, bb0, bb1);
        (void)a0; (void)bb0;

        __hip_bfloat16* wqb = wpool_bf + (size_t)l * WPL;  // wq|wk|wv packed
        __hip_bfloat16* wob = wqb + (size_t)3 * D * D;
        __hip_bfloat16* w1b = wqb + (size_t)4 * D * D;
        __hip_bfloat16* w2b = w1b + (size_t)DFF * D;

        // fused QKV GEMM: N=1536, 768 blocks, DEEP-pipelined + XCD-swizzled (NBN=12)
        gemm_pipe<3><<<768, 256, 0, stream>>>((const unsigned short*)h_bf,
                                              (const unsigned short*)wqb,
                                              qkvbias + (size_t)l * 1536,
                                              q_bf, kbf, v_bf, ML, 3 * D, D, 12);

        // mscore + acorr bulk clear (8192 + 128 blocks)
        mscore_kernel<<<B * LSEQ + 128, 256, 0, stream>>>(q_bf, kbf, a1, bb1, Mbuf,
                                                          acorr);
        topk_chunk_kernel<<<B * H * 16, 256, 0, stream>>>(Mbuf, cand);
        // fused: top-k merge ∥ vmean partial ∥ flag clear (16 + 128 + 8 blocks)
        topkmerge_vmean_kernel<<<B * H + B * H * 8 + 8, 256, 0, stream>>>(
            cand, top, v_bf, vpart, flags);
        attn_part<<<dim3(NS, H, B), 256, 0, stream>>>(q_bf, kbf, v_bf, top, Opart, msumb);
        // fused: attnred corr scatter (into pre-cleared acorr) ∥ wo_base (720+256)
        attnred_wobase_kernel<<<B * H * U + B * 128, 256, 0, stream>>>(
            Opart, msumb, vpart, (const unsigned short*)wob, top, acorr, flags,
            bo + l * D, baseb);
        add_ln_base_kernel<<<ML, 64, 0, stream>>>(h_bf, baseb, acorr, flags,
                                                  g1 + l * D, b1 + l * D);

        // W1: N=2048, 1024 blocks, DEEP-pipelined + swizzled (NBN=16)
        gemm_pipe<2><<<1024, 256, 0, stream>>>((const unsigned short*)h_bf,
                                               (const unsigned short*)w1b, bf1 + l * DFF,
                                               y1_bf, nullptr, nullptr, ML, DFF, D, 16);
        // W2: m97-shape 128x128 BK=32 + split-K=2, 512 blocks; halves: aout(+bias)/tmp
        gemm_w2b<<<512, 256, 0, stream>>>((const unsigned short*)y1_bf,
                                          (const unsigned short*)w2b, bf2 + l * D,
                                          aout, tmp);
        // LN2 (+ fused final head on the last layer)
        add_ln_kernel<<<ML, 64, 0, stream>>>(h_bf, aout, tmp, g2 + l * D, b2 + l * D,
                                             Wf, bff, out, (l == NL - 1) ? 1 : 0);
    }
}